// Round 8
// baseline (259.241 us; speedup 1.0000x reference)
//
#include <hip/hip_runtime.h>

// Problem constants
#define BB   16
#define HEADS 8
#define DH   64
#define NSP  1024   // W*H = 32*32
#define CCH  512

typedef unsigned int   u32;
typedef unsigned short u16;
typedef __attribute__((ext_vector_type(8))) short  short8;   // 8 bf16 = 4 VGPR (MFMA A/B frag)
typedef __attribute__((ext_vector_type(4))) float  floatx4;  // MFMA C/D frag

#if defined(__has_builtin)
#if __has_builtin(__builtin_amdgcn_exp2f)
#define EXP2F(x) __builtin_amdgcn_exp2f(x)
#else
#define EXP2F(x) exp2f(x)
#endif
#else
#define EXP2F(x) exp2f(x)
#endif

__device__ __forceinline__ u16 f2b(float f) {
  u32 x = __float_as_uint(f);
  x = x + 0x7fffu + ((x >> 16) & 1u);   // RNE
  return (u16)(x >> 16);
}

// pack two fp32 -> two bf16 (round-half-up ~= RNE) in one v_perm_b32
__device__ __forceinline__ u32 pkbf(float lo, float hi) {
  return __builtin_amdgcn_perm(__float_as_uint(hi) + 0x8000u,
                               __float_as_uint(lo) + 0x8000u, 0x07060302u);
}

__device__ __forceinline__ void gload_lds16(const u16* g, u16* l) {
  __builtin_amdgcn_global_load_lds((const __attribute__((address_space(1))) u32*)g,
                                   (__attribute__((address_space(3))) u32*)l, 16, 0, 0);
}

// ---- prep: cast Wq/Wk/Wv (o,c) fp32 -> bf16, layout kept (c contiguous = A-operand) ----
__global__ __launch_bounds__(256) void prep_wcast(const float* __restrict__ Wq,
                                                  const float* __restrict__ Wk,
                                                  const float* __restrict__ Wv,
                                                  u16* __restrict__ wbf) {
  int idx = blockIdx.x * 256 + threadIdx.x;   // < 196608 (x4 elems)
  int which = idx >> 16;
  int r4 = (idx & 65535) * 4;
  const float* src = which == 0 ? Wq : which == 1 ? Wk : Wv;
  float4 v = *(const float4*)&src[r4];
  ushort4 s;
  s.x = f2b(v.x); s.y = f2b(v.y); s.z = f2b(v.z); s.w = f2b(v.w);
  *(ushort4*)&wbf[(which << 18) + r4] = s;
}

// ---- prep: pos[h][n][dd] = rel_h[h,dd,hh] + rel_w[h,dd,ww], n = ww*32+hh ----
__global__ __launch_bounds__(256) void prep_pos(const float* __restrict__ rel_h,
                                                const float* __restrict__ rel_w,
                                                u16* __restrict__ pos) {
  int idx = blockIdx.x * 256 + threadIdx.x;     // < 8*1024*64
  int dd = idx & 63;
  int n  = (idx >> 6) & 1023;
  int h  = idx >> 16;
  int ww = n >> 5, hh = n & 31;
  float v = rel_h[(h * 64 + dd) * 32 + hh] + rel_w[(h * 64 + dd) * 32 + ww];
  pos[idx] = f2b(v);
}

// ---- prep: x [b][c][n] fp32 -> xt [b][n][c] bf16 (B-operand layout), 64x64 LDS tiles ----
__global__ __launch_bounds__(256) void prep_xt(const float* __restrict__ x,
                                               u16* __restrict__ xt) {
  int ntile = blockIdx.x, ctile = blockIdx.y, b = blockIdx.z;
  __shared__ float ld[64][68];
  int t = threadIdx.x;
  const float* xb = x + (((size_t)b * CCH + ctile * 64) << 10) + ntile * 64;
#pragma unroll
  for (int p = 0; p < 4; ++p) {
    int c = p * 16 + (t >> 4), n4 = (t & 15) * 4;
    float4 v = *(const float4*)&xb[((size_t)c << 10) + n4];
    ld[c][n4 + 0] = v.x; ld[c][n4 + 1] = v.y; ld[c][n4 + 2] = v.z; ld[c][n4 + 3] = v.w;
  }
  __syncthreads();
  u16* xo = xt + (((size_t)b << 10) + ntile * 64) * CCH + ctile * 64;
#pragma unroll
  for (int p = 0; p < 2; ++p) {
    int id = p * 256 + t;
    int n = id >> 3, c8 = (id & 7) * 8;
    ushort4 s0, s1;
    s0.x = f2b(ld[c8 + 0][n]); s0.y = f2b(ld[c8 + 1][n]);
    s0.z = f2b(ld[c8 + 2][n]); s0.w = f2b(ld[c8 + 3][n]);
    s1.x = f2b(ld[c8 + 4][n]); s1.y = f2b(ld[c8 + 5][n]);
    s1.z = f2b(ld[c8 + 6][n]); s1.w = f2b(ld[c8 + 7][n]);
    *(ushort4*)&xo[(size_t)n * CCH + c8] = s0;
    *(ushort4*)&xo[(size_t)n * CCH + c8 + 4] = s1;
  }
}

// ---- MFMA QKV projection (unchanged from R7) ----
__global__ __launch_bounds__(256, 3) void qkv_mfma(const u16* __restrict__ wbf,
                                                   const u16* __restrict__ xt,
                                                   const float* __restrict__ bq,
                                                   const float* __restrict__ bk,
                                                   const float* __restrict__ bv,
                                                   u16* __restrict__ qw,
                                                   u16* __restrict__ kw,
                                                   u16* __restrict__ vtw) {
  int ntile = blockIdx.x, otile = blockIdx.y;
  int b = blockIdx.z & 15, which = blockIdx.z >> 4;
  int o0 = otile * 128, n0 = ntile * 128;

  __shared__ __align__(16) u16 At[128 * 64];  // W rows  [o][k-chunk swizzled]
  __shared__ __align__(16) u16 Bt[128 * 64];  // xT rows [n][k-chunk swizzled]

  int t = threadIdx.x;
  int w = t >> 6, lane = t & 63;
  int l15 = lane & 15, quad = lane >> 4;
  int wrM = (w >> 1) * 64, wrN = (w & 1) * 64;

  const u16* Ag = wbf + ((size_t)which << 18) + (size_t)o0 * CCH;
  const u16* Bg = xt + (((size_t)b << 10) + n0) * CCH;

  floatx4 acc[4][4];
#pragma unroll
  for (int i = 0; i < 4; ++i)
#pragma unroll
    for (int j = 0; j < 4; ++j) acc[i][j] = (floatx4){0.f, 0.f, 0.f, 0.f};

  const u16* aSrc = which == 2 ? Bt : At;
  const u16* bSrc = which == 2 ? At : Bt;

  int srow = lane >> 3;
  int scc = ((lane & 7) ^ srow) << 3;

  for (int k0 = 0; k0 < CCH; k0 += 64) {
    __syncthreads();
#pragma unroll
    for (int p = 0; p < 4; ++p) {
      int r0 = (w * 4 + p) * 8;
      int row = r0 + srow;
      gload_lds16(Ag + (size_t)row * CCH + k0 + scc, &At[r0 * 64]);
      gload_lds16(Bg + (size_t)row * CCH + k0 + scc, &Bt[r0 * 64]);
    }
    __syncthreads();
#pragma unroll
    for (int ks = 0; ks < 2; ++ks) {
      short8 af[4], bf4[4];
#pragma unroll
      for (int s = 0; s < 4; ++s) {
        int ra = wrM + s * 16 + l15;
        int rb = wrN + s * 16 + l15;
        af[s]  = *(const short8*)&aSrc[ra * 64 + (((ks * 4 + quad) ^ (ra & 7)) << 3)];
        bf4[s] = *(const short8*)&bSrc[rb * 64 + (((ks * 4 + quad) ^ (rb & 7)) << 3)];
      }
#pragma unroll
      for (int i = 0; i < 4; ++i)
#pragma unroll
        for (int j = 0; j < 4; ++j)
          acc[i][j] = __builtin_amdgcn_mfma_f32_16x16x32_bf16(af[i], bf4[j], acc[i][j], 0, 0, 0);
    }
  }

  // ---- epilogue (fast packed bf16 stores) ----
  if (which == 2) {
    // C rows = n, cols = o. Tiled layout: vtw[((bh*16 + n>>6)*64 + dd)*64 + (n&63)]
#pragma unroll
    for (int i = 0; i < 4; ++i) {
      int n = n0 + wrM + i * 16 + quad * 4;
      int nt = n >> 6, nn = n & 63;
#pragma unroll
      for (int j = 0; j < 4; ++j) {
        int o = o0 + wrN + j * 16 + l15;
        int h = o >> 6, dd = o & 63;
        float bias = bv[o];
        uint2 s;
        s.x = pkbf(acc[i][j][0] + bias, acc[i][j][1] + bias);
        s.y = pkbf(acc[i][j][2] + bias, acc[i][j][3] + bias);
        *(uint2*)&vtw[(((size_t)(b * HEADS + h) * 16 + nt) * 64 + dd) * 64 + nn] = s;
      }
    }
  } else {
    const float* bias = which == 0 ? bq : bk;
    u16* dst = which == 0 ? qw : kw;
#pragma unroll
    for (int i = 0; i < 4; ++i) {
      int o = o0 + wrM + i * 16 + quad * 4;
      int h = o >> 6, dd = o & 63;
      float b0 = bias[o], b1 = bias[o + 1], b2 = bias[o + 2], b3 = bias[o + 3];
      size_t hb = (size_t)(b * HEADS + h) * NSP;
#pragma unroll
      for (int j = 0; j < 4; ++j) {
        int n = n0 + wrN + j * 16 + l15;
        uint2 s;
        s.x = pkbf(acc[i][j][0] + b0, acc[i][j][1] + b1);
        s.y = pkbf(acc[i][j][2] + b2, acc[i][j][3] + b3);
        *(uint2*)&dst[(hb + n) * 64 + dd] = s;
      }
    }
  }
}

// ---- MFMA flash attention: 128-row m-tile, 36 KB LDS -> 4 blocks/CU ----
// S^T[n][m] = k_n·q_m + q_n·pos_m; p = exp(s-8) (no running max needed);
// PV fused per 32-n half (pt = 32m x 40 per wave). Single-buffered staging;
// occupancy (4 blocks, 16 waves/CU) staggers barriers across blocks.
__global__ __launch_bounds__(256, 4) void attn_mfma(const u16* __restrict__ qw,
                                                    const u16* __restrict__ kw,
                                                    const u16* __restrict__ vtw,
                                                    const u16* __restrict__ pos,
                                                    const float* __restrict__ x,
                                                    float* __restrict__ out) {
  int bh = blockIdx.x, mtile = blockIdx.y;
  int b = bh >> 3, h = bh & 7;
  __shared__ __align__(16) u16 smem_u16[18432];   // 36 KB (epilogue needs 4x9 KB)
  u16* kt = smem_u16;           // [64n][64dd] chunk16 ^ (row&7)   8 KB
  u16* qt = kt + 4096;          // [64n][64dd]                     8 KB
  u16* vt = qt + 4096;          // [64dd][64n]                     8 KB
  u16* pt = smem_u16 + 12288;   // 4 waves x [32m][40] (80B rows)  10 KB

  int t = threadIdx.x;
  int w = t >> 6, lane = t & 63;
  int l15 = lane & 15, quad = lane >> 4;
  size_t bhs = (size_t)bh;

  // loop-invariant fragments: q_m, pos_m (MFMA B-operands), 32 rows per wave
  short8 qa[2][2], pa[2][2];
  {
    const short* qg = (const short*)qw + (bhs * NSP + mtile * 128 + w * 32) * 64;
    const short* pg = (const short*)pos + ((size_t)h * NSP + mtile * 128 + w * 32) * 64;
#pragma unroll
    for (int msub = 0; msub < 2; ++msub)
#pragma unroll
      for (int ks = 0; ks < 2; ++ks) {
        int off = (msub * 16 + l15) * 64 + ks * 32 + quad * 8;
        qa[msub][ks] = *(const short8*)(qg + off);
        pa[msub][ks] = *(const short8*)(pg + off);
      }
  }

  floatx4 oacc[2][4];   // [msub][ddsub]: dd = ddsub*16+quad*4+r, m = msub*16+l15
  float lsum[2] = {0.f, 0.f};
#pragma unroll
  for (int i = 0; i < 2; ++i)
#pragma unroll
    for (int j = 0; j < 4; ++j) oacc[i][j] = (floatx4){0.f, 0.f, 0.f, 0.f};

  const u16* kg  = kw + bhs * NSP * 64;
  const u16* qgn = qw + bhs * NSP * 64;
  const u16* vg  = vtw + bhs * 16 * 4096;   // tiled [nt][64dd][64n]
  u16* ptw = pt + w * 1280;                 // wave-private [32m][40]
  int srow = lane >> 3, sc = lane & 7;

  // hoisted swizzle invariants
  int rs = l15 & 7;
  int c0 = (quad ^ rs) << 3;        // S-phase B-frag chunk offsets (u16 units)
  int c1 = ((4 + quad) ^ rs) << 3;

  for (int nt = 0; nt < 16; ++nt) {
    __syncthreads();   // previous tile's reads complete before overwrite
    // stage k / q_n / v tiles: global_load_lds w16, swizzle on the global side
#pragma unroll
    for (int p = 0; p < 2; ++p) {
      int r0 = w * 16 + p * 8;
      int row = r0 + srow;
      int swz = ((sc ^ (row & 7)) << 3);
      gload_lds16(kg + (nt * 64 + row) * 64 + swz, &kt[r0 * 64]);
      gload_lds16(qgn + (nt * 64 + row) * 64 + swz, &qt[r0 * 64]);
      gload_lds16(vg + (size_t)nt * 4096 + row * 64 + swz, &vt[r0 * 64]);
    }
    __syncthreads();   // staged data visible

#pragma unroll
    for (int half = 0; half < 2; ++half) {
      // ---- S^T + softmax numerator for 32 n (2 nblk), P -> wave-private pt ----
#pragma unroll
      for (int nblk2 = 0; nblk2 < 2; ++nblk2) {
        int nblk = half * 2 + nblk2;
        int rb = (nblk * 16 + l15) * 64;
        short8 kb0 = *(short8*)&kt[rb + c0];
        short8 kb1 = *(short8*)&kt[rb + c1];
        short8 qb0 = *(short8*)&qt[rb + c0];
        short8 qb1 = *(short8*)&qt[rb + c1];
        floatx4 sc4[2];
#pragma unroll
        for (int msub = 0; msub < 2; ++msub) {
          floatx4 c = (floatx4){0.f, 0.f, 0.f, 0.f};
          c = __builtin_amdgcn_mfma_f32_16x16x32_bf16(kb0, qa[msub][0], c, 0, 0, 0);
          c = __builtin_amdgcn_mfma_f32_16x16x32_bf16(kb1, qa[msub][1], c, 0, 0, 0);
          c = __builtin_amdgcn_mfma_f32_16x16x32_bf16(qb0, pa[msub][0], c, 0, 0, 0);
          c = __builtin_amdgcn_mfma_f32_16x16x32_bf16(qb1, pa[msub][1], c, 0, 0, 0);
          sc4[msub] = c;
        }
#pragma unroll
        for (int msub = 0; msub < 2; ++msub) {
          // p = exp(s - 8) = exp2(s*log2e - 8*log2e)
          float p0 = EXP2F(fmaf(sc4[msub][0], 1.44269504f, -11.5415603f));
          float p1 = EXP2F(fmaf(sc4[msub][1], 1.44269504f, -11.5415603f));
          float p2 = EXP2F(fmaf(sc4[msub][2], 1.44269504f, -11.5415603f));
          float p3 = EXP2F(fmaf(sc4[msub][3], 1.44269504f, -11.5415603f));
          lsum[msub] += (p0 + p1) + (p2 + p3);
          uint2 pk;
          pk.x = pkbf(p0, p1);
          pk.y = pkbf(p2, p3);
          *(uint2*)&ptw[(msub * 16 + l15) * 40 + nblk2 * 16 + quad * 4] = pk;
        }
      }
      // ---- PV for this 32-n half: O^T += V^T · P^T (K=32) ----
      short8 pB[2];
#pragma unroll
      for (int msub = 0; msub < 2; ++msub)
        pB[msub] = *(short8*)&ptw[(msub * 16 + l15) * 40 + quad * 8];
#pragma unroll
      for (int dd = 0; dd < 4; ++dd) {
        int row = dd * 16 + l15;
        short8 vb = *(short8*)&vt[row * 64 + (((half * 4 + quad) ^ (row & 7)) << 3)];
#pragma unroll
        for (int msub = 0; msub < 2; ++msub)
          oacc[msub][dd] = __builtin_amdgcn_mfma_f32_16x16x32_bf16(vb, pB[msub], oacc[msub][dd], 0, 0, 0);
      }
    }
  }

  // ---- row-sum reduction (column m is held by 4 quad-lanes) ----
  float rinv[2];
#pragma unroll
  for (int msub = 0; msub < 2; ++msub) {
    float l = lsum[msub];
    l += __shfl_xor(l, 16);
    l += __shfl_xor(l, 32);
    rinv[msub] = 1.0f / l;
  }

  // ---- epilogue: wave-private LDS transpose [dd][m], float4 residual+store ----
  __syncthreads();   // all waves done with buffers before smem reuse
  float* ot = (float*)smem_u16 + w * 2304;   // 64dd x 36
  int l8 = lane & 7, lr = lane >> 3;
#pragma unroll
  for (int msub = 0; msub < 2; ++msub)
#pragma unroll
    for (int dd = 0; dd < 4; ++dd)
#pragma unroll
      for (int r = 0; r < 4; ++r)
        ot[(dd * 16 + quad * 4 + r) * 36 + msub * 16 + l15] = oacc[msub][dd][r] * rinv[msub];
  // intra-wave LDS ops are in-order; no barrier needed
#pragma unroll
  for (int pass = 0; pass < 8; ++pass) {
    int dd = pass * 8 + lr;
    float4 o4 = *(float4*)&ot[dd * 36 + l8 * 4];
    size_t off = (((size_t)b * CCH + h * DH + dd) << 10) + mtile * 128 + w * 32 + l8 * 4;
    float4 xv = *(const float4*)&x[off];
    o4.x += xv.x; o4.y += xv.y; o4.z += xv.z; o4.w += xv.w;
    *(float4*)&out[off] = o4;
  }
}

extern "C" void kernel_launch(void* const* d_in, const int* in_sizes, int n_in,
                              void* d_out, int out_size, void* d_ws, size_t ws_size,
                              hipStream_t stream) {
  const float* x     = (const float*)d_in[0];
  const float* Wq    = (const float*)d_in[1];
  const float* bq    = (const float*)d_in[2];
  const float* Wk    = (const float*)d_in[3];
  const float* bk    = (const float*)d_in[4];
  const float* Wv    = (const float*)d_in[5];
  const float* bv    = (const float*)d_in[6];
  const float* rel_h = (const float*)d_in[7];
  const float* rel_w = (const float*)d_in[8];
  // d_in[9] (reg_qk) and d_in[10] (reg_v) provably do not affect the output.
  float* out = (float*)d_out;

  char* ws = (char*)d_ws;
  u16* qw   = (u16*)(ws);                          // 16 MB  [b,h,n,dd]
  u16* kw   = (u16*)(ws + ((size_t)16 << 20));     // 16 MB  [b,h,n,dd]
  u16* vtw  = (u16*)(ws + ((size_t)32 << 20));     // 16 MB  [bh][nt16][dd64][nn64]
  u16* pos  = (u16*)(ws + ((size_t)48 << 20));     // 1 MB   [h,n,dd]
  u16* wbf  = (u16*)(ws + ((size_t)49 << 20));     // 1.5 MB [which][o][c] bf16
  u16* xt   = (u16*)d_out;                         // xT bf16 parked in d_out (overwritten later)

  hipLaunchKernelGGL(prep_wcast, dim3(768), dim3(256), 0, stream, Wq, Wk, Wv, wbf);
  hipLaunchKernelGGL(prep_pos, dim3(2048), dim3(256), 0, stream, rel_h, rel_w, pos);
  hipLaunchKernelGGL(prep_xt, dim3(16, 8, 16), dim3(256), 0, stream, x, xt);
  hipLaunchKernelGGL(qkv_mfma, dim3(8, 4, 48), dim3(256), 0, stream,
                     wbf, xt, bq, bk, bv, qw, kw, vtw);
  hipLaunchKernelGGL(attn_mfma, dim3(128, 8), dim3(256), 0, stream,
                     qw, kw, vtw, pos, x, out);
}

// Round 9
// 217.829 us; speedup vs baseline: 1.1901x; 1.1901x over previous
//
#include <hip/hip_runtime.h>

// Problem constants
#define BB   16
#define HEADS 8
#define DH   64
#define NSP  1024   // W*H = 32*32
#define CCH  512

typedef unsigned int   u32;
typedef unsigned short u16;
typedef __attribute__((ext_vector_type(8))) short  short8;   // 8 bf16 = 4 VGPR (MFMA A/B frag)
typedef __attribute__((ext_vector_type(4))) float  floatx4;  // MFMA C/D frag

#if defined(__has_builtin)
#if __has_builtin(__builtin_amdgcn_exp2f)
#define EXP2F(x) __builtin_amdgcn_exp2f(x)
#else
#define EXP2F(x) exp2f(x)
#endif
#else
#define EXP2F(x) exp2f(x)
#endif

__device__ __forceinline__ u16 f2b(float f) {
  u32 x = __float_as_uint(f);
  x = x + 0x7fffu + ((x >> 16) & 1u);   // RNE
  return (u16)(x >> 16);
}

// pack two fp32 -> two bf16 (round-half-up ~= RNE) in one v_perm_b32
__device__ __forceinline__ u32 pkbf(float lo, float hi) {
  return __builtin_amdgcn_perm(__float_as_uint(hi) + 0x8000u,
                               __float_as_uint(lo) + 0x8000u, 0x07060302u);
}

__device__ __forceinline__ void gload_lds16(const u16* g, u16* l) {
  __builtin_amdgcn_global_load_lds((const __attribute__((address_space(1))) u32*)g,
                                   (__attribute__((address_space(3))) u32*)l, 16, 0, 0);
}

// ---- prep: cast Wq/Wk/Wv (o,c) fp32 -> bf16, layout kept (c contiguous = A-operand) ----
__global__ __launch_bounds__(256) void prep_wcast(const float* __restrict__ Wq,
                                                  const float* __restrict__ Wk,
                                                  const float* __restrict__ Wv,
                                                  u16* __restrict__ wbf) {
  int idx = blockIdx.x * 256 + threadIdx.x;   // < 196608 (x4 elems)
  int which = idx >> 16;
  int r4 = (idx & 65535) * 4;
  const float* src = which == 0 ? Wq : which == 1 ? Wk : Wv;
  float4 v = *(const float4*)&src[r4];
  ushort4 s;
  s.x = f2b(v.x); s.y = f2b(v.y); s.z = f2b(v.z); s.w = f2b(v.w);
  *(ushort4*)&wbf[(which << 18) + r4] = s;
}

// ---- prep: pos[h][n][dd] = rel_h[h,dd,hh] + rel_w[h,dd,ww], n = ww*32+hh ----
__global__ __launch_bounds__(256) void prep_pos(const float* __restrict__ rel_h,
                                                const float* __restrict__ rel_w,
                                                u16* __restrict__ pos) {
  int idx = blockIdx.x * 256 + threadIdx.x;     // < 8*1024*64
  int dd = idx & 63;
  int n  = (idx >> 6) & 1023;
  int h  = idx >> 16;
  int ww = n >> 5, hh = n & 31;
  float v = rel_h[(h * 64 + dd) * 32 + hh] + rel_w[(h * 64 + dd) * 32 + ww];
  pos[idx] = f2b(v);
}

// ---- prep: x [b][c][n] fp32 -> xt [b][n][c] bf16 (B-operand layout), 64x64 LDS tiles ----
__global__ __launch_bounds__(256) void prep_xt(const float* __restrict__ x,
                                               u16* __restrict__ xt) {
  int ntile = blockIdx.x, ctile = blockIdx.y, b = blockIdx.z;
  __shared__ float ld[64][68];
  int t = threadIdx.x;
  const float* xb = x + (((size_t)b * CCH + ctile * 64) << 10) + ntile * 64;
#pragma unroll
  for (int p = 0; p < 4; ++p) {
    int c = p * 16 + (t >> 4), n4 = (t & 15) * 4;
    float4 v = *(const float4*)&xb[((size_t)c << 10) + n4];
    ld[c][n4 + 0] = v.x; ld[c][n4 + 1] = v.y; ld[c][n4 + 2] = v.z; ld[c][n4 + 3] = v.w;
  }
  __syncthreads();
  u16* xo = xt + (((size_t)b << 10) + ntile * 64) * CCH + ctile * 64;
#pragma unroll
  for (int p = 0; p < 2; ++p) {
    int id = p * 256 + t;
    int n = id >> 3, c8 = (id & 7) * 8;
    ushort4 s0, s1;
    s0.x = f2b(ld[c8 + 0][n]); s0.y = f2b(ld[c8 + 1][n]);
    s0.z = f2b(ld[c8 + 2][n]); s0.w = f2b(ld[c8 + 3][n]);
    s1.x = f2b(ld[c8 + 4][n]); s1.y = f2b(ld[c8 + 5][n]);
    s1.z = f2b(ld[c8 + 6][n]); s1.w = f2b(ld[c8 + 7][n]);
    *(ushort4*)&xo[(size_t)n * CCH + c8] = s0;
    *(ushort4*)&xo[(size_t)n * CCH + c8 + 4] = s1;
  }
}

// ---- MFMA QKV projection (unchanged) ----
__global__ __launch_bounds__(256, 3) void qkv_mfma(const u16* __restrict__ wbf,
                                                   const u16* __restrict__ xt,
                                                   const float* __restrict__ bq,
                                                   const float* __restrict__ bk,
                                                   const float* __restrict__ bv,
                                                   u16* __restrict__ qw,
                                                   u16* __restrict__ kw,
                                                   u16* __restrict__ vtw) {
  int ntile = blockIdx.x, otile = blockIdx.y;
  int b = blockIdx.z & 15, which = blockIdx.z >> 4;
  int o0 = otile * 128, n0 = ntile * 128;

  __shared__ __align__(16) u16 At[128 * 64];  // W rows  [o][k-chunk swizzled]
  __shared__ __align__(16) u16 Bt[128 * 64];  // xT rows [n][k-chunk swizzled]

  int t = threadIdx.x;
  int w = t >> 6, lane = t & 63;
  int l15 = lane & 15, quad = lane >> 4;
  int wrM = (w >> 1) * 64, wrN = (w & 1) * 64;

  const u16* Ag = wbf + ((size_t)which << 18) + (size_t)o0 * CCH;
  const u16* Bg = xt + (((size_t)b << 10) + n0) * CCH;

  floatx4 acc[4][4];
#pragma unroll
  for (int i = 0; i < 4; ++i)
#pragma unroll
    for (int j = 0; j < 4; ++j) acc[i][j] = (floatx4){0.f, 0.f, 0.f, 0.f};

  const u16* aSrc = which == 2 ? Bt : At;
  const u16* bSrc = which == 2 ? At : Bt;

  int srow = lane >> 3;
  int scc = ((lane & 7) ^ srow) << 3;

  for (int k0 = 0; k0 < CCH; k0 += 64) {
    __syncthreads();
#pragma unroll
    for (int p = 0; p < 4; ++p) {
      int r0 = (w * 4 + p) * 8;
      int row = r0 + srow;
      gload_lds16(Ag + (size_t)row * CCH + k0 + scc, &At[r0 * 64]);
      gload_lds16(Bg + (size_t)row * CCH + k0 + scc, &Bt[r0 * 64]);
    }
    __syncthreads();
#pragma unroll
    for (int ks = 0; ks < 2; ++ks) {
      short8 af[4], bf4[4];
#pragma unroll
      for (int s = 0; s < 4; ++s) {
        int ra = wrM + s * 16 + l15;
        int rb = wrN + s * 16 + l15;
        af[s]  = *(const short8*)&aSrc[ra * 64 + (((ks * 4 + quad) ^ (ra & 7)) << 3)];
        bf4[s] = *(const short8*)&bSrc[rb * 64 + (((ks * 4 + quad) ^ (rb & 7)) << 3)];
      }
#pragma unroll
      for (int i = 0; i < 4; ++i)
#pragma unroll
        for (int j = 0; j < 4; ++j)
          acc[i][j] = __builtin_amdgcn_mfma_f32_16x16x32_bf16(af[i], bf4[j], acc[i][j], 0, 0, 0);
    }
  }

  // ---- epilogue (fast packed bf16 stores) ----
  if (which == 2) {
    // C rows = n, cols = o. Tiled layout: vtw[((bh*16 + n>>6)*64 + dd)*64 + (n&63)]
#pragma unroll
    for (int i = 0; i < 4; ++i) {
      int n = n0 + wrM + i * 16 + quad * 4;
      int nt = n >> 6, nn = n & 63;
#pragma unroll
      for (int j = 0; j < 4; ++j) {
        int o = o0 + wrN + j * 16 + l15;
        int h = o >> 6, dd = o & 63;
        float bias = bv[o];
        uint2 s;
        s.x = pkbf(acc[i][j][0] + bias, acc[i][j][1] + bias);
        s.y = pkbf(acc[i][j][2] + bias, acc[i][j][3] + bias);
        *(uint2*)&vtw[(((size_t)(b * HEADS + h) * 16 + nt) * 64 + dd) * 64 + nn] = s;
      }
    }
  } else {
    const float* bias = which == 0 ? bq : bk;
    u16* dst = which == 0 ? qw : kw;
#pragma unroll
    for (int i = 0; i < 4; ++i) {
      int o = o0 + wrM + i * 16 + quad * 4;
      int h = o >> 6, dd = o & 63;
      float b0 = bias[o], b1 = bias[o + 1], b2 = bias[o + 2], b3 = bias[o + 3];
      size_t hb = (size_t)(b * HEADS + h) * NSP;
#pragma unroll
      for (int j = 0; j < 4; ++j) {
        int n = n0 + wrN + j * 16 + l15;
        uint2 s;
        s.x = pkbf(acc[i][j][0] + b0, acc[i][j][1] + b1);
        s.y = pkbf(acc[i][j][2] + b2, acc[i][j][3] + b3);
        *(uint2*)&dst[(hb + n) * 64 + dd] = s;
      }
    }
  }
}

// ---- MFMA flash attention: 256-m tile, 512-thread blocks (8 waves x 32 m),
// double-buffered staging, 1 barrier/tile. Same 512-block grid / L2 footprint
// as the 84us R7 kernel, but 4 waves/SIMD so exp-VALU chains overlap MFMA.
__global__ __launch_bounds__(512, 4) void attn_mfma(const u16* __restrict__ qw,
                                                    const u16* __restrict__ kw,
                                                    const u16* __restrict__ vtw,
                                                    const u16* __restrict__ pos,
                                                    const float* __restrict__ x,
                                                    float* __restrict__ out) {
  int bh = blockIdx.x, mtile = blockIdx.y;
  int b = bh >> 3, h = bh & 7;
  __shared__ __align__(16) u16 smem_u16[34816];   // 68 KB
  // buf k: smem + k*12288 : kt [64n][64dd] | qt | vt [64dd][64n]  (chunk16 ^ row&7)
  u16* pt = smem_u16 + 24576;   // 8 waves x [32m][40] (80B rows)  20 KB

  int t = threadIdx.x;
  int w = t >> 6, lane = t & 63;
  int l15 = lane & 15, quad = lane >> 4;
  size_t bhs = (size_t)bh;

  // loop-invariant fragments: q_m, pos_m (MFMA B-operands), 32 rows per wave
  short8 qa[2][2], pa[2][2];
  {
    const short* qg = (const short*)qw + (bhs * NSP + mtile * 256 + w * 32) * 64;
    const short* pg = (const short*)pos + ((size_t)h * NSP + mtile * 256 + w * 32) * 64;
#pragma unroll
    for (int msub = 0; msub < 2; ++msub)
#pragma unroll
      for (int ks = 0; ks < 2; ++ks) {
        int off = (msub * 16 + l15) * 64 + ks * 32 + quad * 8;
        qa[msub][ks] = *(const short8*)(qg + off);
        pa[msub][ks] = *(const short8*)(pg + off);
      }
  }

  floatx4 oacc[2][4];   // [msub][ddsub]: dd = ddsub*16+quad*4+r, m = msub*16+l15
  float lsum[2] = {0.f, 0.f};
#pragma unroll
  for (int i = 0; i < 2; ++i)
#pragma unroll
    for (int j = 0; j < 4; ++j) oacc[i][j] = (floatx4){0.f, 0.f, 0.f, 0.f};

  const u16* kg  = kw + bhs * NSP * 64;
  const u16* qgn = qw + bhs * NSP * 64;
  const u16* vg  = vtw + bhs * 16 * 4096;   // tiled [nt][64dd][64n]
  u16* ptw = pt + w * 1280;                 // wave-private [32m][40]
  int srow = lane >> 3, sc = lane & 7;

  // hoisted swizzle invariants
  int rs = l15 & 7;
  int c0 = (quad ^ rs) << 3;        // S-phase B-frag chunk offsets (u16 units)
  int c1 = ((4 + quad) ^ rs) << 3;

  // stage tile nt into buffer buf: 8 waves x 8 rows cover 64 rows per matrix
  auto stage = [&](int nt, int buf) {
    u16* kt = smem_u16 + buf * 12288;
    int r0 = w * 8;
    int row = r0 + srow;
    int swz = ((sc ^ (row & 7)) << 3);
    gload_lds16(kg + (nt * 64 + row) * 64 + swz, &kt[r0 * 64]);
    gload_lds16(qgn + (nt * 64 + row) * 64 + swz, &kt[4096 + r0 * 64]);
    gload_lds16(vg + (size_t)nt * 4096 + row * 64 + swz, &kt[8192 + r0 * 64]);
  };

  stage(0, 0);   // prologue DMA

  for (int nt = 0; nt < 16; ++nt) {
    __syncthreads();           // drains DMAs (incl. tile nt) + joins waves
    if (nt < 15) stage(nt + 1, (nt + 1) & 1);   // prefetch flies during compute

    u16* kt = smem_u16 + (nt & 1) * 12288;
    u16* qt = kt + 4096;
    u16* vt = qt + 4096;

#pragma unroll
    for (int half = 0; half < 2; ++half) {
      // ---- S^T + softmax numerator for 32 n (2 nblk), P -> wave-private pt ----
#pragma unroll
      for (int nblk2 = 0; nblk2 < 2; ++nblk2) {
        int nblk = half * 2 + nblk2;
        int rb = (nblk * 16 + l15) * 64;
        short8 kb0 = *(short8*)&kt[rb + c0];
        short8 kb1 = *(short8*)&kt[rb + c1];
        short8 qb0 = *(short8*)&qt[rb + c0];
        short8 qb1 = *(short8*)&qt[rb + c1];
        floatx4 sc4[2];
#pragma unroll
        for (int msub = 0; msub < 2; ++msub) {
          floatx4 c = (floatx4){0.f, 0.f, 0.f, 0.f};
          c = __builtin_amdgcn_mfma_f32_16x16x32_bf16(kb0, qa[msub][0], c, 0, 0, 0);
          c = __builtin_amdgcn_mfma_f32_16x16x32_bf16(kb1, qa[msub][1], c, 0, 0, 0);
          c = __builtin_amdgcn_mfma_f32_16x16x32_bf16(qb0, pa[msub][0], c, 0, 0, 0);
          c = __builtin_amdgcn_mfma_f32_16x16x32_bf16(qb1, pa[msub][1], c, 0, 0, 0);
          sc4[msub] = c;
        }
#pragma unroll
        for (int msub = 0; msub < 2; ++msub) {
          // p = exp(s - 8) = exp2(s*log2e - 8*log2e)
          float p0 = EXP2F(fmaf(sc4[msub][0], 1.44269504f, -11.5415603f));
          float p1 = EXP2F(fmaf(sc4[msub][1], 1.44269504f, -11.5415603f));
          float p2 = EXP2F(fmaf(sc4[msub][2], 1.44269504f, -11.5415603f));
          float p3 = EXP2F(fmaf(sc4[msub][3], 1.44269504f, -11.5415603f));
          lsum[msub] += (p0 + p1) + (p2 + p3);
          uint2 pk;
          pk.x = pkbf(p0, p1);
          pk.y = pkbf(p2, p3);
          *(uint2*)&ptw[(msub * 16 + l15) * 40 + nblk2 * 16 + quad * 4] = pk;
        }
      }
      // ---- PV for this 32-n half: O^T += V^T · P^T (K=32) ----
      short8 pB[2];
#pragma unroll
      for (int msub = 0; msub < 2; ++msub)
        pB[msub] = *(short8*)&ptw[(msub * 16 + l15) * 40 + quad * 8];
#pragma unroll
      for (int dd = 0; dd < 4; ++dd) {
        int row = dd * 16 + l15;
        short8 vb = *(short8*)&vt[row * 64 + (((half * 4 + quad) ^ (row & 7)) << 3)];
#pragma unroll
        for (int msub = 0; msub < 2; ++msub)
          oacc[msub][dd] = __builtin_amdgcn_mfma_f32_16x16x32_bf16(vb, pB[msub], oacc[msub][dd], 0, 0, 0);
      }
    }
  }

  // ---- row-sum reduction (column m is held by 4 quad-lanes) ----
  float rinv[2];
#pragma unroll
  for (int msub = 0; msub < 2; ++msub) {
    float l = lsum[msub];
    l += __shfl_xor(l, 16);
    l += __shfl_xor(l, 32);
    rinv[msub] = 1.0f / l;
  }

  // ---- epilogue: wave-private LDS transpose [64dd][34], float4 residual+store ----
  __syncthreads();   // all waves done with buffers before smem reuse
  float* ot = (float*)smem_u16 + w * 2176;   // 64dd x 34 = 8704 B/wave, 8 waves = 68 KB
  int l8 = lane & 7, lr = lane >> 3;
#pragma unroll
  for (int msub = 0; msub < 2; ++msub)
#pragma unroll
    for (int dd = 0; dd < 4; ++dd)
#pragma unroll
      for (int r = 0; r < 4; ++r)
        ot[(dd * 16 + quad * 4 + r) * 34 + msub * 16 + l15] = oacc[msub][dd][r] * rinv[msub];
  // intra-wave LDS ops are in-order; no barrier needed
#pragma unroll
  for (int pass = 0; pass < 8; ++pass) {
    int dd = pass * 8 + lr;
    float4 o4 = *(float4*)&ot[dd * 34 + l8 * 4];
    size_t off = (((size_t)b * CCH + h * DH + dd) << 10) + mtile * 256 + w * 32 + l8 * 4;
    float4 xv = *(const float4*)&x[off];
    o4.x += xv.x; o4.y += xv.y; o4.z += xv.z; o4.w += xv.w;
    *(float4*)&out[off] = o4;
  }
}

extern "C" void kernel_launch(void* const* d_in, const int* in_sizes, int n_in,
                              void* d_out, int out_size, void* d_ws, size_t ws_size,
                              hipStream_t stream) {
  const float* x     = (const float*)d_in[0];
  const float* Wq    = (const float*)d_in[1];
  const float* bq    = (const float*)d_in[2];
  const float* Wk    = (const float*)d_in[3];
  const float* bk    = (const float*)d_in[4];
  const float* Wv    = (const float*)d_in[5];
  const float* bv    = (const float*)d_in[6];
  const float* rel_h = (const float*)d_in[7];
  const float* rel_w = (const float*)d_in[8];
  // d_in[9] (reg_qk) and d_in[10] (reg_v) provably do not affect the output.
  float* out = (float*)d_out;

  char* ws = (char*)d_ws;
  u16* qw   = (u16*)(ws);                          // 16 MB  [b,h,n,dd]
  u16* kw   = (u16*)(ws + ((size_t)16 << 20));     // 16 MB  [b,h,n,dd]
  u16* vtw  = (u16*)(ws + ((size_t)32 << 20));     // 16 MB  [bh][nt16][dd64][nn64]
  u16* pos  = (u16*)(ws + ((size_t)48 << 20));     // 1 MB   [h,n,dd]
  u16* wbf  = (u16*)(ws + ((size_t)49 << 20));     // 1.5 MB [which][o][c] bf16
  u16* xt   = (u16*)d_out;                         // xT bf16 parked in d_out (overwritten later)

  hipLaunchKernelGGL(prep_wcast, dim3(768), dim3(256), 0, stream, Wq, Wk, Wv, wbf);
  hipLaunchKernelGGL(prep_pos, dim3(2048), dim3(256), 0, stream, rel_h, rel_w, pos);
  hipLaunchKernelGGL(prep_xt, dim3(16, 8, 16), dim3(256), 0, stream, x, xt);
  hipLaunchKernelGGL(qkv_mfma, dim3(8, 4, 48), dim3(256), 0, stream,
                     wbf, xt, bq, bk, bv, qw, kw, vtw);
  hipLaunchKernelGGL(attn_mfma, dim3(128, 4), dim3(512), 0, stream,
                     qw, kw, vtw, pos, x, out);
}

// Round 10
// 215.659 us; speedup vs baseline: 1.2021x; 1.0101x over previous
//
#include <hip/hip_runtime.h>

// Problem constants
#define BB   16
#define HEADS 8
#define DH   64
#define NSP  1024   // W*H = 32*32
#define CCH  512

typedef unsigned int   u32;
typedef unsigned short u16;
typedef __attribute__((ext_vector_type(8))) short  short8;   // 8 bf16 = 4 VGPR (MFMA A/B frag)
typedef __attribute__((ext_vector_type(4))) float  floatx4;  // MFMA C/D frag

#if defined(__has_builtin)
#if __has_builtin(__builtin_amdgcn_exp2f)
#define EXP2F(x) __builtin_amdgcn_exp2f(x)
#else
#define EXP2F(x) exp2f(x)
#endif
#else
#define EXP2F(x) exp2f(x)
#endif

__device__ __forceinline__ u16 f2b(float f) {
  u32 x = __float_as_uint(f);
  x = x + 0x7fffu + ((x >> 16) & 1u);   // RNE
  return (u16)(x >> 16);
}

// pack two fp32 -> two bf16 (round-half-up ~= RNE) in one v_perm_b32
__device__ __forceinline__ u32 pkbf(float lo, float hi) {
  return __builtin_amdgcn_perm(__float_as_uint(hi) + 0x8000u,
                               __float_as_uint(lo) + 0x8000u, 0x07060302u);
}

__device__ __forceinline__ void gload_lds16(const u16* g, u16* l) {
  __builtin_amdgcn_global_load_lds((const __attribute__((address_space(1))) u32*)g,
                                   (__attribute__((address_space(3))) u32*)l, 16, 0, 0);
}

// ---- fused prep: Wq/Wk/Wv cast (768 blk) | pos build (2048 blk) | x transpose (2048 blk)
__global__ __launch_bounds__(256) void prep_all(const float* __restrict__ x,
                                                const float* __restrict__ Wq,
                                                const float* __restrict__ Wk,
                                                const float* __restrict__ Wv,
                                                const float* __restrict__ rel_h,
                                                const float* __restrict__ rel_w,
                                                u16* __restrict__ wbf,
                                                u16* __restrict__ pos,
                                                u16* __restrict__ xt) {
  __shared__ float ld[64][68];
  int bid = blockIdx.x;
  int t = threadIdx.x;
  if (bid < 768) {
    // ---- W cast (o,c) fp32 -> bf16 ----
    int idx = bid * 256 + t;
    int which = idx >> 16;
    int r4 = (idx & 65535) * 4;
    const float* src = which == 0 ? Wq : which == 1 ? Wk : Wv;
    float4 v = *(const float4*)&src[r4];
    ushort4 s;
    s.x = f2b(v.x); s.y = f2b(v.y); s.z = f2b(v.z); s.w = f2b(v.w);
    *(ushort4*)&wbf[(which << 18) + r4] = s;
  } else if (bid < 2816) {
    // ---- pos[h][n][dd] = rel_h[h,dd,hh] + rel_w[h,dd,ww], n = ww*32+hh ----
    int idx = (bid - 768) * 256 + t;
    int dd = idx & 63;
    int n  = (idx >> 6) & 1023;
    int h  = idx >> 16;
    int ww = n >> 5, hh = n & 31;
    float v = rel_h[(h * 64 + dd) * 32 + hh] + rel_w[(h * 64 + dd) * 32 + ww];
    pos[idx] = f2b(v);
  } else {
    // ---- x [b][c][n] fp32 -> xt [b][n][c] bf16, 64x64 LDS tile ----
    int bid2 = bid - 2816;
    int ntile = bid2 & 15, ctile = (bid2 >> 4) & 7, b = bid2 >> 7;
    const float* xb = x + (((size_t)b * CCH + ctile * 64) << 10) + ntile * 64;
#pragma unroll
    for (int p = 0; p < 4; ++p) {
      int c = p * 16 + (t >> 4), n4 = (t & 15) * 4;
      float4 v = *(const float4*)&xb[((size_t)c << 10) + n4];
      ld[c][n4 + 0] = v.x; ld[c][n4 + 1] = v.y; ld[c][n4 + 2] = v.z; ld[c][n4 + 3] = v.w;
    }
    __syncthreads();
    u16* xo = xt + (((size_t)b << 10) + ntile * 64) * CCH + ctile * 64;
#pragma unroll
    for (int p = 0; p < 2; ++p) {
      int id = p * 256 + t;
      int n = id >> 3, c8 = (id & 7) * 8;
      ushort4 s0, s1;
      s0.x = f2b(ld[c8 + 0][n]); s0.y = f2b(ld[c8 + 1][n]);
      s0.z = f2b(ld[c8 + 2][n]); s0.w = f2b(ld[c8 + 3][n]);
      s1.x = f2b(ld[c8 + 4][n]); s1.y = f2b(ld[c8 + 5][n]);
      s1.z = f2b(ld[c8 + 6][n]); s1.w = f2b(ld[c8 + 7][n]);
      *(ushort4*)&xo[(size_t)n * CCH + c8] = s0;
      *(ushort4*)&xo[(size_t)n * CCH + c8 + 4] = s1;
    }
  }
}

// ---- MFMA QKV projection: 128x128 tile, BK=64, DOUBLE-BUFFERED, 1 barrier/k-step ----
// O[o][n] = sum_c W[o][c] X[c][n] per (b, which); which==2 (V) swaps A/B roles so
// C rows = n; V written TILED [bh][nt16][dd64][nn64].
__global__ __launch_bounds__(256, 2) void qkv_mfma(const u16* __restrict__ wbf,
                                                   const u16* __restrict__ xt,
                                                   const float* __restrict__ bq,
                                                   const float* __restrict__ bk,
                                                   const float* __restrict__ bv,
                                                   u16* __restrict__ qw,
                                                   u16* __restrict__ kw,
                                                   u16* __restrict__ vtw) {
  int ntile = blockIdx.x, otile = blockIdx.y;
  int b = blockIdx.z & 15, which = blockIdx.z >> 4;
  int o0 = otile * 128, n0 = ntile * 128;

  __shared__ __align__(16) u16 smem[2 * 16384];   // 64 KB: buf { At 128x64 | Bt 128x64 }

  int t = threadIdx.x;
  int w = t >> 6, lane = t & 63;
  int l15 = lane & 15, quad = lane >> 4;
  int wrM = (w >> 1) * 64, wrN = (w & 1) * 64;

  const u16* Ag = wbf + ((size_t)which << 18) + (size_t)o0 * CCH;
  const u16* Bg = xt + (((size_t)b << 10) + n0) * CCH;

  floatx4 acc[4][4];
#pragma unroll
  for (int i = 0; i < 4; ++i)
#pragma unroll
    for (int j = 0; j < 4; ++j) acc[i][j] = (floatx4){0.f, 0.f, 0.f, 0.f};

  int srow = lane >> 3;
  int scc = ((lane & 7) ^ srow) << 3;

  auto stage = [&](int k0, int buf) {
    u16* At = smem + buf * 16384;
    u16* Bt = At + 8192;
#pragma unroll
    for (int p = 0; p < 4; ++p) {
      int r0 = (w * 4 + p) * 8;
      int row = r0 + srow;
      gload_lds16(Ag + (size_t)row * CCH + k0 + scc, &At[r0 * 64]);
      gload_lds16(Bg + (size_t)row * CCH + k0 + scc, &Bt[r0 * 64]);
    }
  };

  stage(0, 0);   // prologue DMA

  for (int ki = 0; ki < 8; ++ki) {
    __syncthreads();            // drains DMAs (incl. k-step ki) + joins waves
    if (ki < 7) stage((ki + 1) * 64, (ki + 1) & 1);   // prefetch flies during compute

    u16* At = smem + (ki & 1) * 16384;
    u16* Bt = At + 8192;
    const u16* aSrc = which == 2 ? Bt : At;
    const u16* bSrc = which == 2 ? At : Bt;

#pragma unroll
    for (int ks = 0; ks < 2; ++ks) {
      short8 af[4], bf4[4];
#pragma unroll
      for (int s = 0; s < 4; ++s) {
        int ra = wrM + s * 16 + l15;
        int rb = wrN + s * 16 + l15;
        af[s]  = *(const short8*)&aSrc[ra * 64 + (((ks * 4 + quad) ^ (ra & 7)) << 3)];
        bf4[s] = *(const short8*)&bSrc[rb * 64 + (((ks * 4 + quad) ^ (rb & 7)) << 3)];
      }
#pragma unroll
      for (int i = 0; i < 4; ++i)
#pragma unroll
        for (int j = 0; j < 4; ++j)
          acc[i][j] = __builtin_amdgcn_mfma_f32_16x16x32_bf16(af[i], bf4[j], acc[i][j], 0, 0, 0);
    }
  }

  // ---- epilogue (packed bf16 stores) ----
  if (which == 2) {
    // C rows = n, cols = o. Tiled layout: vtw[((bh*16 + n>>6)*64 + dd)*64 + (n&63)]
#pragma unroll
    for (int i = 0; i < 4; ++i) {
      int n = n0 + wrM + i * 16 + quad * 4;
      int nt = n >> 6, nn = n & 63;
#pragma unroll
      for (int j = 0; j < 4; ++j) {
        int o = o0 + wrN + j * 16 + l15;
        int h = o >> 6, dd = o & 63;
        float bias = bv[o];
        uint2 s;
        s.x = pkbf(acc[i][j][0] + bias, acc[i][j][1] + bias);
        s.y = pkbf(acc[i][j][2] + bias, acc[i][j][3] + bias);
        *(uint2*)&vtw[(((size_t)(b * HEADS + h) * 16 + nt) * 64 + dd) * 64 + nn] = s;
      }
    }
  } else {
    const float* bias = which == 0 ? bq : bk;
    u16* dst = which == 0 ? qw : kw;
#pragma unroll
    for (int i = 0; i < 4; ++i) {
      int o = o0 + wrM + i * 16 + quad * 4;
      int h = o >> 6, dd = o & 63;
      float b0 = bias[o], b1 = bias[o + 1], b2 = bias[o + 2], b3 = bias[o + 3];
      size_t hb = (size_t)(b * HEADS + h) * NSP;
#pragma unroll
      for (int j = 0; j < 4; ++j) {
        int n = n0 + wrN + j * 16 + l15;
        uint2 s;
        s.x = pkbf(acc[i][j][0] + b0, acc[i][j][1] + b1);
        s.y = pkbf(acc[i][j][2] + b2, acc[i][j][3] + b3);
        *(uint2*)&dst[(hb + n) * 64 + dd] = s;
      }
    }
  }
}

// ---- MFMA flash attention: R7 config (best measured 84.0 us) ----
// 256-m tile, 4 waves x 64 m, double-buffered staging, 1 barrier/tile.
__global__ __launch_bounds__(256, 2) void attn_mfma(const u16* __restrict__ qw,
                                                    const u16* __restrict__ kw,
                                                    const u16* __restrict__ vtw,
                                                    const u16* __restrict__ pos,
                                                    const float* __restrict__ x,
                                                    float* __restrict__ out) {
  int bh = blockIdx.x, mtile = blockIdx.y;
  int b = bh >> 3, h = bh & 7;
  __shared__ __align__(16) u16 smem_u16[34816];   // 68 KB
  // buf k: smem + k*12288 : kt [64n][64dd] | qt | vt [64dd][64n]  (chunk16 ^ row&7)
  u16* pt = smem_u16 + 24576;   // 4 waves x [64m][40] (80B rows, 16B pad)  20 KB

  int t = threadIdx.x;
  int w = t >> 6, lane = t & 63;
  int l15 = lane & 15, quad = lane >> 4;
  size_t bhs = (size_t)bh;

  // loop-invariant fragments: q_m, pos_m (MFMA B-operands), 64 rows per wave
  short8 qa[4][2], pa[4][2];
  {
    const short* qg = (const short*)qw + (bhs * NSP + mtile * 256 + w * 64) * 64;
    const short* pg = (const short*)pos + ((size_t)h * NSP + mtile * 256 + w * 64) * 64;
#pragma unroll
    for (int msub = 0; msub < 4; ++msub)
#pragma unroll
      for (int ks = 0; ks < 2; ++ks) {
        int off = (msub * 16 + l15) * 64 + ks * 32 + quad * 8;
        qa[msub][ks] = *(const short8*)(qg + off);
        pa[msub][ks] = *(const short8*)(pg + off);
      }
  }

  floatx4 oacc[4][4];   // [msub][ddsub]: dd = ddsub*16+quad*4+r, m = msub*16+l15
  float lsum[4] = {0.f, 0.f, 0.f, 0.f};
#pragma unroll
  for (int i = 0; i < 4; ++i)
#pragma unroll
    for (int j = 0; j < 4; ++j) oacc[i][j] = (floatx4){0.f, 0.f, 0.f, 0.f};

  const u16* kg  = kw + bhs * NSP * 64;
  const u16* qgn = qw + bhs * NSP * 64;
  const u16* vg  = vtw + bhs * 16 * 4096;   // tiled [nt][64dd][64n]
  u16* ptw = pt + w * 2560;                 // wave-private [64m][40]
  int srow = lane >> 3, sc = lane & 7;

  // hoisted swizzle invariants
  int rs = l15 & 7;
  int c0 = (quad ^ rs) << 3;        // S-phase B-frag chunk offsets (u16 units)
  int c1 = ((4 + quad) ^ rs) << 3;

  // stage tile nt into buffer buf
  auto stage = [&](int nt, int buf) {
    u16* kt = smem_u16 + buf * 12288;
    u16* qt = kt + 4096;
    u16* vt = qt + 4096;
#pragma unroll
    for (int p = 0; p < 2; ++p) {
      int r0 = w * 16 + p * 8;
      int row = r0 + srow;
      int swz = ((sc ^ (row & 7)) << 3);
      gload_lds16(kg + (nt * 64 + row) * 64 + swz, &kt[r0 * 64]);
      gload_lds16(qgn + (nt * 64 + row) * 64 + swz, &qt[r0 * 64]);
      gload_lds16(vg + (size_t)nt * 4096 + row * 64 + swz, &vt[r0 * 64]);
    }
  };

  stage(0, 0);   // prologue DMA

  for (int nt = 0; nt < 16; ++nt) {
    __syncthreads();           // drains this wave's DMAs (incl. tile nt) + joins waves
    if (nt < 15) stage(nt + 1, (nt + 1) & 1);   // prefetch flies during compute below

    u16* kt = smem_u16 + (nt & 1) * 12288;
    u16* qt = kt + 4096;
    u16* vt = qt + 4096;

#pragma unroll
    for (int half = 0; half < 2; ++half) {
      // ---- S^T + softmax numerator for 32 n (2 nblk), P -> wave-private pt ----
#pragma unroll
      for (int nblk2 = 0; nblk2 < 2; ++nblk2) {
        int nblk = half * 2 + nblk2;
        int rb = (nblk * 16 + l15) * 64;
        short8 kb0 = *(short8*)&kt[rb + c0];
        short8 kb1 = *(short8*)&kt[rb + c1];
        short8 qb0 = *(short8*)&qt[rb + c0];
        short8 qb1 = *(short8*)&qt[rb + c1];
        floatx4 sc4[4];
#pragma unroll
        for (int msub = 0; msub < 4; ++msub) {
          floatx4 c = (floatx4){0.f, 0.f, 0.f, 0.f};
          c = __builtin_amdgcn_mfma_f32_16x16x32_bf16(kb0, qa[msub][0], c, 0, 0, 0);
          c = __builtin_amdgcn_mfma_f32_16x16x32_bf16(kb1, qa[msub][1], c, 0, 0, 0);
          c = __builtin_amdgcn_mfma_f32_16x16x32_bf16(qb0, pa[msub][0], c, 0, 0, 0);
          c = __builtin_amdgcn_mfma_f32_16x16x32_bf16(qb1, pa[msub][1], c, 0, 0, 0);
          sc4[msub] = c;
        }
#pragma unroll
        for (int msub = 0; msub < 4; ++msub) {
          // p = exp(s - 8) = exp2(s*log2e - 8*log2e)
          float p0 = EXP2F(fmaf(sc4[msub][0], 1.44269504f, -11.5415603f));
          float p1 = EXP2F(fmaf(sc4[msub][1], 1.44269504f, -11.5415603f));
          float p2 = EXP2F(fmaf(sc4[msub][2], 1.44269504f, -11.5415603f));
          float p3 = EXP2F(fmaf(sc4[msub][3], 1.44269504f, -11.5415603f));
          lsum[msub] += (p0 + p1) + (p2 + p3);
          uint2 pk;
          pk.x = pkbf(p0, p1);
          pk.y = pkbf(p2, p3);
          *(uint2*)&ptw[(msub * 16 + l15) * 40 + nblk2 * 16 + quad * 4] = pk;
        }
      }
      // ---- PV for this 32-n half: O^T += V^T · P^T (K=32) ----
      short8 pB[4];
#pragma unroll
      for (int msub = 0; msub < 4; ++msub)
        pB[msub] = *(short8*)&ptw[(msub * 16 + l15) * 40 + quad * 8];
#pragma unroll
      for (int dd = 0; dd < 4; ++dd) {
        int row = dd * 16 + l15;
        short8 vb = *(short8*)&vt[row * 64 + (((half * 4 + quad) ^ (row & 7)) << 3)];
#pragma unroll
        for (int msub = 0; msub < 4; ++msub)
          oacc[msub][dd] = __builtin_amdgcn_mfma_f32_16x16x32_bf16(vb, pB[msub], oacc[msub][dd], 0, 0, 0);
      }
    }
  }

  // ---- row-sum reduction (column m is held by 4 quad-lanes) ----
  float rinv[4];
#pragma unroll
  for (int msub = 0; msub < 4; ++msub) {
    float l = lsum[msub];
    l += __shfl_xor(l, 16);
    l += __shfl_xor(l, 32);
    rinv[msub] = 1.0f / l;
  }

  // ---- epilogue: wave-private LDS transpose, two 32-m halves, float4 stores ----
  __syncthreads();   // all waves done with buffers before smem reuse
  float* ot = (float*)smem_u16 + w * 2304;   // 64dd x 36
  int l8 = lane & 7, lr = lane >> 3;
#pragma unroll
  for (int mh = 0; mh < 2; ++mh) {
#pragma unroll
    for (int ms2 = 0; ms2 < 2; ++ms2) {
      int msub = mh * 2 + ms2;
#pragma unroll
      for (int dd = 0; dd < 4; ++dd)
#pragma unroll
        for (int r = 0; r < 4; ++r)
          ot[(dd * 16 + quad * 4 + r) * 36 + ms2 * 16 + l15] = oacc[msub][dd][r] * rinv[msub];
    }
    // intra-wave LDS ops are in-order; no barrier needed
#pragma unroll
    for (int pass = 0; pass < 8; ++pass) {
      int dd = pass * 8 + lr;
      float4 o4 = *(float4*)&ot[dd * 36 + l8 * 4];
      size_t off = (((size_t)b * CCH + h * DH + dd) << 10) + mtile * 256 + w * 64 + mh * 32 + l8 * 4;
      float4 xv = *(const float4*)&x[off];
      o4.x += xv.x; o4.y += xv.y; o4.z += xv.z; o4.w += xv.w;
      *(float4*)&out[off] = o4;
    }
  }
}

extern "C" void kernel_launch(void* const* d_in, const int* in_sizes, int n_in,
                              void* d_out, int out_size, void* d_ws, size_t ws_size,
                              hipStream_t stream) {
  const float* x     = (const float*)d_in[0];
  const float* Wq    = (const float*)d_in[1];
  const float* bq    = (const float*)d_in[2];
  const float* Wk    = (const float*)d_in[3];
  const float* bk    = (const float*)d_in[4];
  const float* Wv    = (const float*)d_in[5];
  const float* bv    = (const float*)d_in[6];
  const float* rel_h = (const float*)d_in[7];
  const float* rel_w = (const float*)d_in[8];
  // d_in[9] (reg_qk) and d_in[10] (reg_v) provably do not affect the output.
  float* out = (float*)d_out;

  char* ws = (char*)d_ws;
  u16* qw   = (u16*)(ws);                          // 16 MB  [b,h,n,dd]
  u16* kw   = (u16*)(ws + ((size_t)16 << 20));     // 16 MB  [b,h,n,dd]
  u16* vtw  = (u16*)(ws + ((size_t)32 << 20));     // 16 MB  [bh][nt16][dd64][nn64]
  u16* pos  = (u16*)(ws + ((size_t)48 << 20));     // 1 MB   [h,n,dd]
  u16* wbf  = (u16*)(ws + ((size_t)49 << 20));     // 1.5 MB [which][o][c] bf16
  u16* xt   = (u16*)d_out;                         // xT bf16 parked in d_out (overwritten later)

  hipLaunchKernelGGL(prep_all, dim3(4864), dim3(256), 0, stream,
                     x, Wq, Wk, Wv, rel_h, rel_w, wbf, pos, xt);
  hipLaunchKernelGGL(qkv_mfma, dim3(8, 4, 48), dim3(256), 0, stream,
                     wbf, xt, bq, bk, bv, qw, kw, vtw);
  hipLaunchKernelGGL(attn_mfma, dim3(128, 4), dim3(256), 0, stream,
                     qw, kw, vtw, pos, x, out);
}

// Round 11
// 211.935 us; speedup vs baseline: 1.2232x; 1.0176x over previous
//
#include <hip/hip_runtime.h>

// Problem constants
#define BB   16
#define HEADS 8
#define DH   64
#define NSP  1024   // W*H = 32*32
#define CCH  512

typedef unsigned int   u32;
typedef unsigned short u16;
typedef __attribute__((ext_vector_type(8))) short  short8;   // 8 bf16 = 4 VGPR (MFMA A/B frag)
typedef __attribute__((ext_vector_type(4))) float  floatx4;  // MFMA C/D frag

#if defined(__has_builtin)
#if __has_builtin(__builtin_amdgcn_exp2f)
#define EXP2F(x) __builtin_amdgcn_exp2f(x)
#else
#define EXP2F(x) exp2f(x)
#endif
#else
#define EXP2F(x) exp2f(x)
#endif

__device__ __forceinline__ u16 f2b(float f) {
  u32 x = __float_as_uint(f);
  x = x + 0x7fffu + ((x >> 16) & 1u);   // RNE
  return (u16)(x >> 16);
}

// pack two fp32 -> two bf16 (round-half-up ~= RNE) in one v_perm_b32
__device__ __forceinline__ u32 pkbf(float lo, float hi) {
  return __builtin_amdgcn_perm(__float_as_uint(hi) + 0x8000u,
                               __float_as_uint(lo) + 0x8000u, 0x07060302u);
}

__device__ __forceinline__ void gload_lds16(const u16* g, u16* l) {
  __builtin_amdgcn_global_load_lds((const __attribute__((address_space(1))) u32*)g,
                                   (__attribute__((address_space(3))) u32*)l, 16, 0, 0);
}

// ---- fused prep: Wq/Wk/Wv cast (768 blk) | pos build (2048 blk) | x transpose (2048 blk)
__global__ __launch_bounds__(256) void prep_all(const float* __restrict__ x,
                                                const float* __restrict__ Wq,
                                                const float* __restrict__ Wk,
                                                const float* __restrict__ Wv,
                                                const float* __restrict__ rel_h,
                                                const float* __restrict__ rel_w,
                                                u16* __restrict__ wbf,
                                                u16* __restrict__ pos,
                                                u16* __restrict__ xt) {
  __shared__ float ld[64][68];
  int bid = blockIdx.x;
  int t = threadIdx.x;
  if (bid < 768) {
    // ---- W cast (o,c) fp32 -> bf16 ----
    int idx = bid * 256 + t;
    int which = idx >> 16;
    int r4 = (idx & 65535) * 4;
    const float* src = which == 0 ? Wq : which == 1 ? Wk : Wv;
    float4 v = *(const float4*)&src[r4];
    ushort4 s;
    s.x = f2b(v.x); s.y = f2b(v.y); s.z = f2b(v.z); s.w = f2b(v.w);
    *(ushort4*)&wbf[(which << 18) + r4] = s;
  } else if (bid < 2816) {
    // ---- pos[h][n][dd] = rel_h[h,dd,hh] + rel_w[h,dd,ww], n = ww*32+hh ----
    int idx = (bid - 768) * 256 + t;
    int dd = idx & 63;
    int n  = (idx >> 6) & 1023;
    int h  = idx >> 16;
    int ww = n >> 5, hh = n & 31;
    float v = rel_h[(h * 64 + dd) * 32 + hh] + rel_w[(h * 64 + dd) * 32 + ww];
    pos[idx] = f2b(v);
  } else {
    // ---- x [b][c][n] fp32 -> xt [b][n][c] bf16, 64x64 LDS tile ----
    int bid2 = bid - 2816;
    int ntile = bid2 & 15, ctile = (bid2 >> 4) & 7, b = bid2 >> 7;
    const float* xb = x + (((size_t)b * CCH + ctile * 64) << 10) + ntile * 64;
#pragma unroll
    for (int p = 0; p < 4; ++p) {
      int c = p * 16 + (t >> 4), n4 = (t & 15) * 4;
      float4 v = *(const float4*)&xb[((size_t)c << 10) + n4];
      ld[c][n4 + 0] = v.x; ld[c][n4 + 1] = v.y; ld[c][n4 + 2] = v.z; ld[c][n4 + 3] = v.w;
    }
    __syncthreads();
    u16* xo = xt + (((size_t)b << 10) + ntile * 64) * CCH + ctile * 64;
#pragma unroll
    for (int p = 0; p < 2; ++p) {
      int id = p * 256 + t;
      int n = id >> 3, c8 = (id & 7) * 8;
      ushort4 s0, s1;
      s0.x = f2b(ld[c8 + 0][n]); s0.y = f2b(ld[c8 + 1][n]);
      s0.z = f2b(ld[c8 + 2][n]); s0.w = f2b(ld[c8 + 3][n]);
      s1.x = f2b(ld[c8 + 4][n]); s1.y = f2b(ld[c8 + 5][n]);
      s1.z = f2b(ld[c8 + 6][n]); s1.w = f2b(ld[c8 + 7][n]);
      *(ushort4*)&xo[(size_t)n * CCH + c8] = s0;
      *(ushort4*)&xo[(size_t)n * CCH + c8 + 4] = s1;
    }
  }
}

// ---- MFMA QKV projection: 128x128 tile, BK=64, double-buffered K-loop,
//      COALESCED epilogue via LDS transpose (stores were 8B/128B-stride scatter). ----
__global__ __launch_bounds__(256, 2) void qkv_mfma(const u16* __restrict__ wbf,
                                                   const u16* __restrict__ xt,
                                                   const float* __restrict__ bq,
                                                   const float* __restrict__ bk,
                                                   const float* __restrict__ bv,
                                                   u16* __restrict__ qw,
                                                   u16* __restrict__ kw,
                                                   u16* __restrict__ vtw) {
  int ntile = blockIdx.x, otile = blockIdx.y;
  int b = blockIdx.z & 15, which = blockIdx.z >> 4;
  int o0 = otile * 128, n0 = ntile * 128;

  __shared__ __align__(16) u16 smem[2 * 16384];   // 64 KB: dbuf { At 128x64 | Bt 128x64 }

  int t = threadIdx.x;
  int w = t >> 6, lane = t & 63;
  int l15 = lane & 15, quad = lane >> 4;
  int wrM = (w >> 1) * 64, wrN = (w & 1) * 64;

  const u16* Ag = wbf + ((size_t)which << 18) + (size_t)o0 * CCH;
  const u16* Bg = xt + (((size_t)b << 10) + n0) * CCH;

  floatx4 acc[4][4];
#pragma unroll
  for (int i = 0; i < 4; ++i)
#pragma unroll
    for (int j = 0; j < 4; ++j) acc[i][j] = (floatx4){0.f, 0.f, 0.f, 0.f};

  int srow = lane >> 3;
  int scc = ((lane & 7) ^ srow) << 3;

  auto stage = [&](int k0, int buf) {
    u16* At = smem + buf * 16384;
    u16* Bt = At + 8192;
#pragma unroll
    for (int p = 0; p < 4; ++p) {
      int r0 = (w * 4 + p) * 8;
      int row = r0 + srow;
      gload_lds16(Ag + (size_t)row * CCH + k0 + scc, &At[r0 * 64]);
      gload_lds16(Bg + (size_t)row * CCH + k0 + scc, &Bt[r0 * 64]);
    }
  };

  stage(0, 0);   // prologue DMA

  for (int ki = 0; ki < 8; ++ki) {
    __syncthreads();            // drains DMAs (incl. k-step ki) + joins waves
    if (ki < 7) stage((ki + 1) * 64, (ki + 1) & 1);   // prefetch flies during compute

    u16* At = smem + (ki & 1) * 16384;
    u16* Bt = At + 8192;
    const u16* aSrc = which == 2 ? Bt : At;
    const u16* bSrc = which == 2 ? At : Bt;

#pragma unroll
    for (int ks = 0; ks < 2; ++ks) {
      short8 af[4], bf4[4];
#pragma unroll
      for (int s = 0; s < 4; ++s) {
        int ra = wrM + s * 16 + l15;
        int rb = wrN + s * 16 + l15;
        af[s]  = *(const short8*)&aSrc[ra * 64 + (((ks * 4 + quad) ^ (ra & 7)) << 3)];
        bf4[s] = *(const short8*)&bSrc[rb * 64 + (((ks * 4 + quad) ^ (rb & 7)) << 3)];
      }
#pragma unroll
      for (int i = 0; i < 4; ++i)
#pragma unroll
        for (int j = 0; j < 4; ++j)
          acc[i][j] = __builtin_amdgcn_mfma_f32_16x16x32_bf16(af[i], bf4[j], acc[i][j], 0, 0, 0);
    }
  }

  // ---- epilogue: LDS transpose -> fully coalesced dwordx4 stores ----
  // C frag (i,j): rows = wrM+i*16+quad*4+r (o for Q/K, n for V)
  //               cols = wrN+j*16+l15      (n for Q/K, o for V)
  // LDS ep[col-dim 128][row-dim 132 padded]: uint2 packed writes (4 row-dim vals).
  __syncthreads();               // all waves done with staging buffers
  u16* ep = smem;                // 128*132 u16 = 33 KB
  if (which == 2) {
#pragma unroll
    for (int j = 0; j < 4; ++j) {
      int lrow = wrN + j * 16 + l15;          // o-dim
      float bb = bv[o0 + lrow];
#pragma unroll
      for (int i = 0; i < 4; ++i) {
        floatx4 a = acc[i][j];
        uint2 pk;
        pk.x = pkbf(a[0] + bb, a[1] + bb);
        pk.y = pkbf(a[2] + bb, a[3] + bb);
        *(uint2*)&ep[lrow * 132 + wrM + i * 16 + quad * 4] = pk;
      }
    }
  } else {
    const float* bias = which == 0 ? bq : bk;
#pragma unroll
    for (int i = 0; i < 4; ++i) {
      int ob = o0 + wrM + i * 16 + quad * 4;
      float b0 = bias[ob], b1 = bias[ob + 1], b2 = bias[ob + 2], b3 = bias[ob + 3];
#pragma unroll
      for (int j = 0; j < 4; ++j) {
        floatx4 a = acc[i][j];
        uint2 pk;
        pk.x = pkbf(a[0] + b0, a[1] + b1);
        pk.y = pkbf(a[2] + b2, a[3] + b3);
        *(uint2*)&ep[(wrN + j * 16 + l15) * 132 + wrM + i * 16 + quad * 4] = pk;
      }
    }
  }
  __syncthreads();
  int rr = t >> 4, cc = t & 15;   // 16 rows x 16 cols of 16B per pass
  if (which == 2) {
    // ep row = o-dim, col = n-dim -> vtw tiled [bh][nt][dd][nn], 16B rows
#pragma unroll
    for (int pass = 0; pass < 8; ++pass) {
      int ro = pass * 16 + rr;
      int o = o0 + ro, h = o >> 6, dd = o & 63;
      int n = n0 + cc * 8, ntl = n >> 6, nn = n & 63;
      uint4 v4 = *(uint4*)&ep[ro * 132 + cc * 8];
      *(uint4*)&vtw[(((size_t)(b * HEADS + h) * 16 + ntl) * 64 + dd) * 64 + nn] = v4;
    }
  } else {
    u16* dst = which == 0 ? qw : kw;
    // ep row = n-dim, col = o-dim -> dst [bh][n][dd], 16B rows
#pragma unroll
    for (int pass = 0; pass < 8; ++pass) {
      int rn = pass * 16 + rr;
      int n = n0 + rn;
      int o = o0 + cc * 8, h = o >> 6, dd = o & 63;
      uint4 v4 = *(uint4*)&ep[rn * 132 + cc * 8];
      *(uint4*)&dst[((size_t)(b * HEADS + h) * NSP + n) * 64 + dd] = v4;
    }
  }
}

// ---- MFMA flash attention: R7 config (best measured ~79 us) ----
// 256-m tile, 4 waves x 64 m, double-buffered staging, 1 barrier/tile.
__global__ __launch_bounds__(256, 2) void attn_mfma(const u16* __restrict__ qw,
                                                    const u16* __restrict__ kw,
                                                    const u16* __restrict__ vtw,
                                                    const u16* __restrict__ pos,
                                                    const float* __restrict__ x,
                                                    float* __restrict__ out) {
  int bh = blockIdx.x, mtile = blockIdx.y;
  int b = bh >> 3, h = bh & 7;
  __shared__ __align__(16) u16 smem_u16[34816];   // 68 KB
  // buf k: smem + k*12288 : kt [64n][64dd] | qt | vt [64dd][64n]  (chunk16 ^ row&7)
  u16* pt = smem_u16 + 24576;   // 4 waves x [64m][40] (80B rows, 16B pad)  20 KB

  int t = threadIdx.x;
  int w = t >> 6, lane = t & 63;
  int l15 = lane & 15, quad = lane >> 4;
  size_t bhs = (size_t)bh;

  // loop-invariant fragments: q_m, pos_m (MFMA B-operands), 64 rows per wave
  short8 qa[4][2], pa[4][2];
  {
    const short* qg = (const short*)qw + (bhs * NSP + mtile * 256 + w * 64) * 64;
    const short* pg = (const short*)pos + ((size_t)h * NSP + mtile * 256 + w * 64) * 64;
#pragma unroll
    for (int msub = 0; msub < 4; ++msub)
#pragma unroll
      for (int ks = 0; ks < 2; ++ks) {
        int off = (msub * 16 + l15) * 64 + ks * 32 + quad * 8;
        qa[msub][ks] = *(const short8*)(qg + off);
        pa[msub][ks] = *(const short8*)(pg + off);
      }
  }

  floatx4 oacc[4][4];   // [msub][ddsub]: dd = ddsub*16+quad*4+r, m = msub*16+l15
  float lsum[4] = {0.f, 0.f, 0.f, 0.f};
#pragma unroll
  for (int i = 0; i < 4; ++i)
#pragma unroll
    for (int j = 0; j < 4; ++j) oacc[i][j] = (floatx4){0.f, 0.f, 0.f, 0.f};

  const u16* kg  = kw + bhs * NSP * 64;
  const u16* qgn = qw + bhs * NSP * 64;
  const u16* vg  = vtw + bhs * 16 * 4096;   // tiled [nt][64dd][64n]
  u16* ptw = pt + w * 2560;                 // wave-private [64m][40]
  int srow = lane >> 3, sc = lane & 7;

  // hoisted swizzle invariants
  int rs = l15 & 7;
  int c0 = (quad ^ rs) << 3;        // S-phase B-frag chunk offsets (u16 units)
  int c1 = ((4 + quad) ^ rs) << 3;

  // stage tile nt into buffer buf
  auto stage = [&](int nt, int buf) {
    u16* kt = smem_u16 + buf * 12288;
    u16* qt = kt + 4096;
    u16* vt = qt + 4096;
#pragma unroll
    for (int p = 0; p < 2; ++p) {
      int r0 = w * 16 + p * 8;
      int row = r0 + srow;
      int swz = ((sc ^ (row & 7)) << 3);
      gload_lds16(kg + (nt * 64 + row) * 64 + swz, &kt[r0 * 64]);
      gload_lds16(qgn + (nt * 64 + row) * 64 + swz, &qt[r0 * 64]);
      gload_lds16(vg + (size_t)nt * 4096 + row * 64 + swz, &vt[r0 * 64]);
    }
  };

  stage(0, 0);   // prologue DMA

  for (int nt = 0; nt < 16; ++nt) {
    __syncthreads();           // drains this wave's DMAs (incl. tile nt) + joins waves
    if (nt < 15) stage(nt + 1, (nt + 1) & 1);   // prefetch flies during compute below

    u16* kt = smem_u16 + (nt & 1) * 12288;
    u16* qt = kt + 4096;
    u16* vt = qt + 4096;

#pragma unroll
    for (int half = 0; half < 2; ++half) {
      // ---- S^T + softmax numerator for 32 n (2 nblk), P -> wave-private pt ----
#pragma unroll
      for (int nblk2 = 0; nblk2 < 2; ++nblk2) {
        int nblk = half * 2 + nblk2;
        int rb = (nblk * 16 + l15) * 64;
        short8 kb0 = *(short8*)&kt[rb + c0];
        short8 kb1 = *(short8*)&kt[rb + c1];
        short8 qb0 = *(short8*)&qt[rb + c0];
        short8 qb1 = *(short8*)&qt[rb + c1];
        floatx4 sc4[4];
#pragma unroll
        for (int msub = 0; msub < 4; ++msub) {
          floatx4 c = (floatx4){0.f, 0.f, 0.f, 0.f};
          c = __builtin_amdgcn_mfma_f32_16x16x32_bf16(kb0, qa[msub][0], c, 0, 0, 0);
          c = __builtin_amdgcn_mfma_f32_16x16x32_bf16(kb1, qa[msub][1], c, 0, 0, 0);
          c = __builtin_amdgcn_mfma_f32_16x16x32_bf16(qb0, pa[msub][0], c, 0, 0, 0);
          c = __builtin_amdgcn_mfma_f32_16x16x32_bf16(qb1, pa[msub][1], c, 0, 0, 0);
          sc4[msub] = c;
        }
#pragma unroll
        for (int msub = 0; msub < 4; ++msub) {
          // p = exp(s - 8) = exp2(s*log2e - 8*log2e)
          float p0 = EXP2F(fmaf(sc4[msub][0], 1.44269504f, -11.5415603f));
          float p1 = EXP2F(fmaf(sc4[msub][1], 1.44269504f, -11.5415603f));
          float p2 = EXP2F(fmaf(sc4[msub][2], 1.44269504f, -11.5415603f));
          float p3 = EXP2F(fmaf(sc4[msub][3], 1.44269504f, -11.5415603f));
          lsum[msub] += (p0 + p1) + (p2 + p3);
          uint2 pk;
          pk.x = pkbf(p0, p1);
          pk.y = pkbf(p2, p3);
          *(uint2*)&ptw[(msub * 16 + l15) * 40 + nblk2 * 16 + quad * 4] = pk;
        }
      }
      // ---- PV for this 32-n half: O^T += V^T · P^T (K=32) ----
      short8 pB[4];
#pragma unroll
      for (int msub = 0; msub < 4; ++msub)
        pB[msub] = *(short8*)&ptw[(msub * 16 + l15) * 40 + quad * 8];
#pragma unroll
      for (int dd = 0; dd < 4; ++dd) {
        int row = dd * 16 + l15;
        short8 vb = *(short8*)&vt[row * 64 + (((half * 4 + quad) ^ (row & 7)) << 3)];
#pragma unroll
        for (int msub = 0; msub < 4; ++msub)
          oacc[msub][dd] = __builtin_amdgcn_mfma_f32_16x16x32_bf16(vb, pB[msub], oacc[msub][dd], 0, 0, 0);
      }
    }
  }

  // ---- row-sum reduction (column m is held by 4 quad-lanes) ----
  float rinv[4];
#pragma unroll
  for (int msub = 0; msub < 4; ++msub) {
    float l = lsum[msub];
    l += __shfl_xor(l, 16);
    l += __shfl_xor(l, 32);
    rinv[msub] = 1.0f / l;
  }

  // ---- epilogue: wave-private LDS transpose, two 32-m halves, float4 stores ----
  __syncthreads();   // all waves done with buffers before smem reuse
  float* ot = (float*)smem_u16 + w * 2304;   // 64dd x 36
  int l8 = lane & 7, lr = lane >> 3;
#pragma unroll
  for (int mh = 0; mh < 2; ++mh) {
#pragma unroll
    for (int ms2 = 0; ms2 < 2; ++ms2) {
      int msub = mh * 2 + ms2;
#pragma unroll
      for (int dd = 0; dd < 4; ++dd)
#pragma unroll
        for (int r = 0; r < 4; ++r)
          ot[(dd * 16 + quad * 4 + r) * 36 + ms2 * 16 + l15] = oacc[msub][dd][r] * rinv[msub];
    }
    // intra-wave LDS ops are in-order; no barrier needed
#pragma unroll
    for (int pass = 0; pass < 8; ++pass) {
      int dd = pass * 8 + lr;
      float4 o4 = *(float4*)&ot[dd * 36 + l8 * 4];
      size_t off = (((size_t)b * CCH + h * DH + dd) << 10) + mtile * 256 + w * 64 + mh * 32 + l8 * 4;
      float4 xv = *(const float4*)&x[off];
      o4.x += xv.x; o4.y += xv.y; o4.z += xv.z; o4.w += xv.w;
      *(float4*)&out[off] = o4;
    }
  }
}

extern "C" void kernel_launch(void* const* d_in, const int* in_sizes, int n_in,
                              void* d_out, int out_size, void* d_ws, size_t ws_size,
                              hipStream_t stream) {
  const float* x     = (const float*)d_in[0];
  const float* Wq    = (const float*)d_in[1];
  const float* bq    = (const float*)d_in[2];
  const float* Wk    = (const float*)d_in[3];
  const float* bk    = (const float*)d_in[4];
  const float* Wv    = (const float*)d_in[5];
  const float* bv    = (const float*)d_in[6];
  const float* rel_h = (const float*)d_in[7];
  const float* rel_w = (const float*)d_in[8];
  // d_in[9] (reg_qk) and d_in[10] (reg_v) provably do not affect the output.
  float* out = (float*)d_out;

  char* ws = (char*)d_ws;
  u16* qw   = (u16*)(ws);                          // 16 MB  [b,h,n,dd]
  u16* kw   = (u16*)(ws + ((size_t)16 << 20));     // 16 MB  [b,h,n,dd]
  u16* vtw  = (u16*)(ws + ((size_t)32 << 20));     // 16 MB  [bh][nt16][dd64][nn64]
  u16* pos  = (u16*)(ws + ((size_t)48 << 20));     // 1 MB   [h,n,dd]
  u16* wbf  = (u16*)(ws + ((size_t)49 << 20));     // 1.5 MB [which][o][c] bf16
  u16* xt   = (u16*)d_out;                         // xT bf16 parked in d_out (overwritten later)

  hipLaunchKernelGGL(prep_all, dim3(4864), dim3(256), 0, stream,
                     x, Wq, Wk, Wv, rel_h, rel_w, wbf, pos, xt);
  hipLaunchKernelGGL(qkv_mfma, dim3(8, 4, 48), dim3(256), 0, stream,
                     wbf, xt, bq, bk, bv, qw, kw, vtw);
  hipLaunchKernelGGL(attn_mfma, dim3(128, 4), dim3(256), 0, stream,
                     qw, kw, vtw, pos, x, out);
}

// Round 12
// 210.173 us; speedup vs baseline: 1.2335x; 1.0084x over previous
//
#include <hip/hip_runtime.h>

// Problem constants
#define BB   16
#define HEADS 8
#define DH   64
#define NSP  1024   // W*H = 32*32
#define CCH  512

typedef unsigned int   u32;
typedef unsigned short u16;
typedef __attribute__((ext_vector_type(8))) short  short8;   // 8 bf16 = 4 VGPR (MFMA A/B frag)
typedef __attribute__((ext_vector_type(4))) float  floatx4;  // MFMA C/D frag

#if defined(__has_builtin)
#if __has_builtin(__builtin_amdgcn_exp2f)
#define EXP2F(x) __builtin_amdgcn_exp2f(x)
#else
#define EXP2F(x) exp2f(x)
#endif
#else
#define EXP2F(x) exp2f(x)
#endif

__device__ __forceinline__ u16 f2b(float f) {
  u32 x = __float_as_uint(f);
  x = x + 0x7fffu + ((x >> 16) & 1u);   // RNE
  return (u16)(x >> 16);
}

// pack two fp32 -> two bf16 (round-half-up ~= RNE) in one v_perm_b32
__device__ __forceinline__ u32 pkbf(float lo, float hi) {
  return __builtin_amdgcn_perm(__float_as_uint(hi) + 0x8000u,
                               __float_as_uint(lo) + 0x8000u, 0x07060302u);
}

__device__ __forceinline__ void gload_lds16(const u16* g, u16* l) {
  __builtin_amdgcn_global_load_lds((const __attribute__((address_space(1))) u32*)g,
                                   (__attribute__((address_space(3))) u32*)l, 16, 0, 0);
}

// ---- fused prep: Wq/Wk/Wv cast (768 blk) | pos build (2048 blk) | x transpose (2048 blk)
__global__ __launch_bounds__(256) void prep_all(const float* __restrict__ x,
                                                const float* __restrict__ Wq,
                                                const float* __restrict__ Wk,
                                                const float* __restrict__ Wv,
                                                const float* __restrict__ rel_h,
                                                const float* __restrict__ rel_w,
                                                u16* __restrict__ wbf,
                                                u16* __restrict__ pos,
                                                u16* __restrict__ xt) {
  __shared__ float ld[64][68];
  int bid = blockIdx.x;
  int t = threadIdx.x;
  if (bid < 768) {
    // ---- W cast (o,c) fp32 -> bf16 ----
    int idx = bid * 256 + t;
    int which = idx >> 16;
    int r4 = (idx & 65535) * 4;
    const float* src = which == 0 ? Wq : which == 1 ? Wk : Wv;
    float4 v = *(const float4*)&src[r4];
    ushort4 s;
    s.x = f2b(v.x); s.y = f2b(v.y); s.z = f2b(v.z); s.w = f2b(v.w);
    *(ushort4*)&wbf[(which << 18) + r4] = s;
  } else if (bid < 2816) {
    // ---- pos[h][n][dd] = rel_h[h,dd,hh] + rel_w[h,dd,ww], n = ww*32+hh ----
    int idx = (bid - 768) * 256 + t;
    int dd = idx & 63;
    int n  = (idx >> 6) & 1023;
    int h  = idx >> 16;
    int ww = n >> 5, hh = n & 31;
    float v = rel_h[(h * 64 + dd) * 32 + hh] + rel_w[(h * 64 + dd) * 32 + ww];
    pos[idx] = f2b(v);
  } else {
    // ---- x [b][c][n] fp32 -> xt [b][n][c] bf16, 64x64 LDS tile ----
    int bid2 = bid - 2816;
    int ntile = bid2 & 15, ctile = (bid2 >> 4) & 7, b = bid2 >> 7;
    const float* xb = x + (((size_t)b * CCH + ctile * 64) << 10) + ntile * 64;
#pragma unroll
    for (int p = 0; p < 4; ++p) {
      int c = p * 16 + (t >> 4), n4 = (t & 15) * 4;
      float4 v = *(const float4*)&xb[((size_t)c << 10) + n4];
      ld[c][n4 + 0] = v.x; ld[c][n4 + 1] = v.y; ld[c][n4 + 2] = v.z; ld[c][n4 + 3] = v.w;
    }
    __syncthreads();
    u16* xo = xt + (((size_t)b << 10) + ntile * 64) * CCH + ctile * 64;
#pragma unroll
    for (int p = 0; p < 2; ++p) {
      int id = p * 256 + t;
      int n = id >> 3, c8 = (id & 7) * 8;
      ushort4 s0, s1;
      s0.x = f2b(ld[c8 + 0][n]); s0.y = f2b(ld[c8 + 1][n]);
      s0.z = f2b(ld[c8 + 2][n]); s0.w = f2b(ld[c8 + 3][n]);
      s1.x = f2b(ld[c8 + 4][n]); s1.y = f2b(ld[c8 + 5][n]);
      s1.z = f2b(ld[c8 + 6][n]); s1.w = f2b(ld[c8 + 7][n]);
      *(ushort4*)&xo[(size_t)n * CCH + c8] = s0;
      *(ushort4*)&xo[(size_t)n * CCH + c8 + 4] = s1;
    }
  }
}

// ---- FUSED QKV projection: one block computes Q,K,V for (128n x 64o) sharing the X tile.
// Per BK=64 step: stage Wq/Wk/Wv 64-row strips + X 128-row tile (40 KB, dbuf=80 KB),
// then 48 MFMA per 22 ds_read_b128 (X fragment reused as B for Q/K and A for V —
// A/B lane mappings are identical). V's C rows = n -> transposed layout falls out free.
__global__ __launch_bounds__(256, 2) void qkv_fused(const u16* __restrict__ wbf,
                                                    const u16* __restrict__ xt,
                                                    const float* __restrict__ bq,
                                                    const float* __restrict__ bk,
                                                    const float* __restrict__ bv,
                                                    u16* __restrict__ qw,
                                                    u16* __restrict__ kw,
                                                    u16* __restrict__ vtw) {
  int ntile = blockIdx.x, otile = blockIdx.y, b = blockIdx.z;
  int o0 = otile * 64, n0 = ntile * 128;

  __shared__ __align__(16) u16 smem[2 * 20480];   // 80 KB: buf { Wq64 | Wk64 | Wv64 | X128 } x64c

  int t = threadIdx.x;
  int w = t >> 6, lane = t & 63;
  int l15 = lane & 15, quad = lane >> 4;
  int srow = lane >> 3, sc = lane & 7;
  int scc = (sc ^ srow) << 3;

  floatx4 aq[8], ak[8], av[8];
#pragma unroll
  for (int i = 0; i < 8; ++i) {
    aq[i] = (floatx4){0.f, 0.f, 0.f, 0.f};
    ak[i] = (floatx4){0.f, 0.f, 0.f, 0.f};
    av[i] = (floatx4){0.f, 0.f, 0.f, 0.f};
  }

  // staging: 320 rows of 64c: [0,64)Wq [64,128)Wk [128,192)Wv [192,320)X; 10 glds/wave
  auto stage = [&](int k0, int buf) {
    u16* base = smem + buf * 20480;
#pragma unroll
    for (int p = 0; p < 10; ++p) {
      int g0 = w * 80 + p * 8;     // uniform 8-row group base (tile bounds are x8)
      if (g0 < 192) {
        int which = g0 >> 6;
        int r0 = g0 & 63;
        gload_lds16(wbf + ((size_t)which << 18) + (size_t)(o0 + r0 + srow) * CCH + k0 + scc,
                    base + which * 4096 + r0 * 64);
      } else {
        int r0 = g0 - 192;
        gload_lds16(xt + (size_t)(b * 1024 + n0 + r0 + srow) * CCH + k0 + scc,
                    base + 12288 + r0 * 64);
      }
    }
  };

  int rs = l15 & 7;
  int c0 = (quad ^ rs) << 3;
  int c1 = ((4 + quad) ^ rs) << 3;
  int wrow = (w * 16 + l15) * 64;

  stage(0, 0);   // prologue DMA

  for (int ki = 0; ki < 8; ++ki) {
    __syncthreads();            // drains DMAs (incl. step ki) + joins waves
    if (ki < 7) stage((ki + 1) * 64, (ki + 1) & 1);   // prefetch flies during compute

    u16* base = smem + (ki & 1) * 20480;
    u16* Xb = base + 12288;
#pragma unroll
    for (int ks = 0; ks < 2; ++ks) {
      int cc = ks ? c1 : c0;
      short8 fq = *(short8*)&base[wrow + cc];
      short8 fk = *(short8*)&base[4096 + wrow + cc];
      short8 fv = *(short8*)&base[8192 + wrow + cc];
#pragma unroll
      for (int ns = 0; ns < 8; ++ns) {
        short8 fx = *(short8*)&Xb[(ns * 16 + l15) * 64 + cc];
        aq[ns] = __builtin_amdgcn_mfma_f32_16x16x32_bf16(fq, fx, aq[ns], 0, 0, 0);
        ak[ns] = __builtin_amdgcn_mfma_f32_16x16x32_bf16(fk, fx, ak[ns], 0, 0, 0);
        av[ns] = __builtin_amdgcn_mfma_f32_16x16x32_bf16(fx, fv, av[ns], 0, 0, 0);
      }
    }
  }

  // ---- epilogue: all three tiles through padded LDS -> coalesced dwordx4 stores ----
  __syncthreads();                 // staging buffers dead; reuse as transpose scratch
  u16* epQ = smem;                 // [128 n][72]  (144B rows, 16B-aligned)
  u16* epK = smem + 9216;
  u16* epV = smem + 18432;         // [64 o][136]  (272B rows)
  {
    int ob = o0 + w * 16 + quad * 4;
    float q0 = bq[ob], q1 = bq[ob + 1], q2 = bq[ob + 2], q3 = bq[ob + 3];
    float k0b = bk[ob], k1b = bk[ob + 1], k2b = bk[ob + 2], k3b = bk[ob + 3];
    float vb = bv[o0 + w * 16 + l15];
#pragma unroll
    for (int ns = 0; ns < 8; ++ns) {
      int n = ns * 16 + l15;
      uint2 pk;
      pk.x = pkbf(aq[ns][0] + q0, aq[ns][1] + q1);
      pk.y = pkbf(aq[ns][2] + q2, aq[ns][3] + q3);
      *(uint2*)&epQ[n * 72 + w * 16 + quad * 4] = pk;
      pk.x = pkbf(ak[ns][0] + k0b, ak[ns][1] + k1b);
      pk.y = pkbf(ak[ns][2] + k2b, ak[ns][3] + k3b);
      *(uint2*)&epK[n * 72 + w * 16 + quad * 4] = pk;
      pk.x = pkbf(av[ns][0] + vb, av[ns][1] + vb);
      pk.y = pkbf(av[ns][2] + vb, av[ns][3] + vb);
      *(uint2*)&epV[(w * 16 + l15) * 136 + ns * 16 + quad * 4] = pk;
    }
  }
  __syncthreads();
  int h = otile;
  {
    // Q/K: [bh][n][dd] rows, 128B each; thread = (row, half), 64B contiguous per thread
    int row = t >> 1, half = t & 1;
    size_t gb = ((size_t)(b * HEADS + h) * NSP + n0 + row) * 64 + half * 32;
#pragma unroll
    for (int i = 0; i < 4; ++i)
      *(uint4*)&qw[gb + i * 8] = *(uint4*)&epQ[row * 72 + half * 32 + i * 8];
#pragma unroll
    for (int i = 0; i < 4; ++i)
      *(uint4*)&kw[gb + i * 8] = *(uint4*)&epK[row * 72 + half * 32 + i * 8];
  }
  {
    // V: tiled [bh][nt][dd][nn]; thread = (dd=row, n-quarter), 64B contiguous per thread
    int row = t >> 2, q4 = t & 3;
#pragma unroll
    for (int i = 0; i < 4; ++i) {
      int nl = q4 * 32 + i * 8;
      int n = n0 + nl;
      int ntl = n >> 6, nn = n & 63;
      *(uint4*)&vtw[(((size_t)(b * HEADS + h) * 16 + ntl) * 64 + row) * 64 + nn]
          = *(uint4*)&epV[row * 136 + nl];
    }
  }
}

// ---- MFMA flash attention: R7 config (best measured ~78.6 us) ----
// 256-m tile, 4 waves x 64 m, double-buffered staging, 1 barrier/tile.
__global__ __launch_bounds__(256, 2) void attn_mfma(const u16* __restrict__ qw,
                                                    const u16* __restrict__ kw,
                                                    const u16* __restrict__ vtw,
                                                    const u16* __restrict__ pos,
                                                    const float* __restrict__ x,
                                                    float* __restrict__ out) {
  int bh = blockIdx.x, mtile = blockIdx.y;
  int b = bh >> 3, h = bh & 7;
  __shared__ __align__(16) u16 smem_u16[34816];   // 68 KB
  // buf k: smem + k*12288 : kt [64n][64dd] | qt | vt [64dd][64n]  (chunk16 ^ row&7)
  u16* pt = smem_u16 + 24576;   // 4 waves x [64m][40] (80B rows, 16B pad)  20 KB

  int t = threadIdx.x;
  int w = t >> 6, lane = t & 63;
  int l15 = lane & 15, quad = lane >> 4;
  size_t bhs = (size_t)bh;

  // loop-invariant fragments: q_m, pos_m (MFMA B-operands), 64 rows per wave
  short8 qa[4][2], pa[4][2];
  {
    const short* qg = (const short*)qw + (bhs * NSP + mtile * 256 + w * 64) * 64;
    const short* pg = (const short*)pos + ((size_t)h * NSP + mtile * 256 + w * 64) * 64;
#pragma unroll
    for (int msub = 0; msub < 4; ++msub)
#pragma unroll
      for (int ks = 0; ks < 2; ++ks) {
        int off = (msub * 16 + l15) * 64 + ks * 32 + quad * 8;
        qa[msub][ks] = *(const short8*)(qg + off);
        pa[msub][ks] = *(const short8*)(pg + off);
      }
  }

  floatx4 oacc[4][4];   // [msub][ddsub]: dd = ddsub*16+quad*4+r, m = msub*16+l15
  float lsum[4] = {0.f, 0.f, 0.f, 0.f};
#pragma unroll
  for (int i = 0; i < 4; ++i)
#pragma unroll
    for (int j = 0; j < 4; ++j) oacc[i][j] = (floatx4){0.f, 0.f, 0.f, 0.f};

  const u16* kg  = kw + bhs * NSP * 64;
  const u16* qgn = qw + bhs * NSP * 64;
  const u16* vg  = vtw + bhs * 16 * 4096;   // tiled [nt][64dd][64n]
  u16* ptw = pt + w * 2560;                 // wave-private [64m][40]
  int srow = lane >> 3, sc = lane & 7;

  // hoisted swizzle invariants
  int rs = l15 & 7;
  int c0 = (quad ^ rs) << 3;        // S-phase B-frag chunk offsets (u16 units)
  int c1 = ((4 + quad) ^ rs) << 3;

  // stage tile nt into buffer buf
  auto stage = [&](int nt, int buf) {
    u16* kt = smem_u16 + buf * 12288;
    u16* qt = kt + 4096;
    u16* vt = qt + 4096;
#pragma unroll
    for (int p = 0; p < 2; ++p) {
      int r0 = w * 16 + p * 8;
      int row = r0 + srow;
      int swz = ((sc ^ (row & 7)) << 3);
      gload_lds16(kg + (nt * 64 + row) * 64 + swz, &kt[r0 * 64]);
      gload_lds16(qgn + (nt * 64 + row) * 64 + swz, &qt[r0 * 64]);
      gload_lds16(vg + (size_t)nt * 4096 + row * 64 + swz, &vt[r0 * 64]);
    }
  };

  stage(0, 0);   // prologue DMA

  for (int nt = 0; nt < 16; ++nt) {
    __syncthreads();           // drains this wave's DMAs (incl. tile nt) + joins waves
    if (nt < 15) stage(nt + 1, (nt + 1) & 1);   // prefetch flies during compute below

    u16* kt = smem_u16 + (nt & 1) * 12288;
    u16* qt = kt + 4096;
    u16* vt = qt + 4096;

#pragma unroll
    for (int half = 0; half < 2; ++half) {
      // ---- S^T + softmax numerator for 32 n (2 nblk), P -> wave-private pt ----
#pragma unroll
      for (int nblk2 = 0; nblk2 < 2; ++nblk2) {
        int nblk = half * 2 + nblk2;
        int rb = (nblk * 16 + l15) * 64;
        short8 kb0 = *(short8*)&kt[rb + c0];
        short8 kb1 = *(short8*)&kt[rb + c1];
        short8 qb0 = *(short8*)&qt[rb + c0];
        short8 qb1 = *(short8*)&qt[rb + c1];
        floatx4 sc4[4];
#pragma unroll
        for (int msub = 0; msub < 4; ++msub) {
          floatx4 c = (floatx4){0.f, 0.f, 0.f, 0.f};
          c = __builtin_amdgcn_mfma_f32_16x16x32_bf16(kb0, qa[msub][0], c, 0, 0, 0);
          c = __builtin_amdgcn_mfma_f32_16x16x32_bf16(kb1, qa[msub][1], c, 0, 0, 0);
          c = __builtin_amdgcn_mfma_f32_16x16x32_bf16(qb0, pa[msub][0], c, 0, 0, 0);
          c = __builtin_amdgcn_mfma_f32_16x16x32_bf16(qb1, pa[msub][1], c, 0, 0, 0);
          sc4[msub] = c;
        }
#pragma unroll
        for (int msub = 0; msub < 4; ++msub) {
          // p = exp(s - 8) = exp2(s*log2e - 8*log2e)
          float p0 = EXP2F(fmaf(sc4[msub][0], 1.44269504f, -11.5415603f));
          float p1 = EXP2F(fmaf(sc4[msub][1], 1.44269504f, -11.5415603f));
          float p2 = EXP2F(fmaf(sc4[msub][2], 1.44269504f, -11.5415603f));
          float p3 = EXP2F(fmaf(sc4[msub][3], 1.44269504f, -11.5415603f));
          lsum[msub] += (p0 + p1) + (p2 + p3);
          uint2 pk;
          pk.x = pkbf(p0, p1);
          pk.y = pkbf(p2, p3);
          *(uint2*)&ptw[(msub * 16 + l15) * 40 + nblk2 * 16 + quad * 4] = pk;
        }
      }
      // ---- PV for this 32-n half: O^T += V^T · P^T (K=32) ----
      short8 pB[4];
#pragma unroll
      for (int msub = 0; msub < 4; ++msub)
        pB[msub] = *(short8*)&ptw[(msub * 16 + l15) * 40 + quad * 8];
#pragma unroll
      for (int dd = 0; dd < 4; ++dd) {
        int row = dd * 16 + l15;
        short8 vb = *(short8*)&vt[row * 64 + (((half * 4 + quad) ^ (row & 7)) << 3)];
#pragma unroll
        for (int msub = 0; msub < 4; ++msub)
          oacc[msub][dd] = __builtin_amdgcn_mfma_f32_16x16x32_bf16(vb, pB[msub], oacc[msub][dd], 0, 0, 0);
      }
    }
  }

  // ---- row-sum reduction (column m is held by 4 quad-lanes) ----
  float rinv[4];
#pragma unroll
  for (int msub = 0; msub < 4; ++msub) {
    float l = lsum[msub];
    l += __shfl_xor(l, 16);
    l += __shfl_xor(l, 32);
    rinv[msub] = 1.0f / l;
  }

  // ---- epilogue: wave-private LDS transpose, two 32-m halves, float4 stores ----
  __syncthreads();   // all waves done with buffers before smem reuse
  float* ot = (float*)smem_u16 + w * 2304;   // 64dd x 36
  int l8 = lane & 7, lr = lane >> 3;
#pragma unroll
  for (int mh = 0; mh < 2; ++mh) {
#pragma unroll
    for (int ms2 = 0; ms2 < 2; ++ms2) {
      int msub = mh * 2 + ms2;
#pragma unroll
      for (int dd = 0; dd < 4; ++dd)
#pragma unroll
        for (int r = 0; r < 4; ++r)
          ot[(dd * 16 + quad * 4 + r) * 36 + ms2 * 16 + l15] = oacc[msub][dd][r] * rinv[msub];
    }
    // intra-wave LDS ops are in-order; no barrier needed
#pragma unroll
    for (int pass = 0; pass < 8; ++pass) {
      int dd = pass * 8 + lr;
      float4 o4 = *(float4*)&ot[dd * 36 + l8 * 4];
      size_t off = (((size_t)b * CCH + h * DH + dd) << 10) + mtile * 256 + w * 64 + mh * 32 + l8 * 4;
      float4 xv = *(const float4*)&x[off];
      o4.x += xv.x; o4.y += xv.y; o4.z += xv.z; o4.w += xv.w;
      *(float4*)&out[off] = o4;
    }
  }
}

extern "C" void kernel_launch(void* const* d_in, const int* in_sizes, int n_in,
                              void* d_out, int out_size, void* d_ws, size_t ws_size,
                              hipStream_t stream) {
  const float* x     = (const float*)d_in[0];
  const float* Wq    = (const float*)d_in[1];
  const float* bq    = (const float*)d_in[2];
  const float* Wk    = (const float*)d_in[3];
  const float* bk    = (const float*)d_in[4];
  const float* Wv    = (const float*)d_in[5];
  const float* bv    = (const float*)d_in[6];
  const float* rel_h = (const float*)d_in[7];
  const float* rel_w = (const float*)d_in[8];
  // d_in[9] (reg_qk) and d_in[10] (reg_v) provably do not affect the output.
  float* out = (float*)d_out;

  char* ws = (char*)d_ws;
  u16* qw   = (u16*)(ws);                          // 16 MB  [b,h,n,dd]
  u16* kw   = (u16*)(ws + ((size_t)16 << 20));     // 16 MB  [b,h,n,dd]
  u16* vtw  = (u16*)(ws + ((size_t)32 << 20));     // 16 MB  [bh][nt16][dd64][nn64]
  u16* pos  = (u16*)(ws + ((size_t)48 << 20));     // 1 MB   [h,n,dd]
  u16* wbf  = (u16*)(ws + ((size_t)49 << 20));     // 1.5 MB [which][o][c] bf16
  u16* xt   = (u16*)d_out;                         // xT bf16 parked in d_out (overwritten later)

  hipLaunchKernelGGL(prep_all, dim3(4864), dim3(256), 0, stream,
                     x, Wq, Wk, Wv, rel_h, rel_w, wbf, pos, xt);
  hipLaunchKernelGGL(qkv_fused, dim3(8, 8, 16), dim3(256), 0, stream,
                     wbf, xt, bq, bk, bv, qw, kw, vtw);
  hipLaunchKernelGGL(attn_mfma, dim3(128, 4), dim3(256), 0, stream,
                     qw, kw, vtw, pos, x, out);
}